// Round 11
// baseline (150.584 us; speedup 1.0000x reference)
//
#include <hip/hip_runtime.h>
#include <math.h>

#define IMG_B 16
#define IMG_H 512
#define IMG_W 512
#define IMG_HW (IMG_H * IMG_W)
#define NPART 2048            // 128 feat blocks/image * 16 images

// moment indices: 0:S_p 1:S_pp 2:S_g 3:S_gg 4:S_pg 5:S_d 6:S_dd 7:S_pd 8:S_t
#define NMOM 9

// 32x32 tile CCL, packed boundary graph: per tile 192 nodes
//   slots 0..127  : ring pixels (ring index map below)
//   slots 128..191: boundary-component roots (compacted)
#define TILES 256             // per image (16x16)
#define NODES_PER_TILE 192
#define NODES_PER_IMG (TILES * NODES_PER_TILE)   // 49152
#define PAIRS 128             // tile pairs per image
#define TOUCH (1 << 30)

struct Scal {
    float gmin, gmax, dmin, dmax;
    double mom[NMOM];
    double area[IMG_B];
    int fgcnt[IMG_B];
    int maxcnt[IMG_B];
};

// ws layout (bytes):
//   0       Scal (padded to 512)
//   512     float4 pmm[NPART]            (32768)
//   33280   double pblk[NPART][NMOM]     (147456)
//   180736  int    pfg[NPART]            (8192)
//   188928  scratch: packed labels / counts / nslot / pairmax
#define OFF_PMM   512
#define OFF_MOM   33280
#define OFF_FG    180736
#define OFF_SCR   188928

// ---- union-find (LDS or global) ----
__device__ __forceinline__ int uf_findv(const int* L, int p) {
    while (true) { const int q = ((volatile const int*)L)[p]; if (q == p) return p; p = q; }
}
__device__ __forceinline__ void uf_merge(int* L, int a, int b) {
    while (true) {
        a = uf_findv(L, a);
        b = uf_findv(L, b);
        if (a == b) return;
        if (a < b) { int t = a; a = b; b = t; }
        const int old = atomicMin(&L[a], b);
        if (old == a) return;
        a = old;
    }
}

// ---- run bit helpers ----
__device__ __forceinline__ int run_start(unsigned m, int b) {
    const unsigned below = ~m & ((b == 0) ? 0u : ((1u << b) - 1u));
    return below ? (int)(32u - (unsigned)__builtin_clz(below)) : 0;
}
__device__ __forceinline__ int run_len(unsigned m, int s) {
    const unsigned inv = ~(m >> s);
    return inv ? __builtin_ctz(inv) : (32 - s);
}
__device__ __forceinline__ int run_idx(unsigned sm, int c) {
    return __popc(sm & (unsigned)((2ull << c) - 1ull)) - 1;
}
// spread 8 bits to stride-4 positions (bit i -> bit 4i)
__device__ __forceinline__ unsigned spread4(unsigned x) {
    x &= 0xFFu;
    x = (x | (x << 12)) & 0x000F000Fu;
    x = (x | (x << 6))  & 0x03030303u;
    x = (x | (x << 3))  & 0x11111111u;
    return x;
}

// ring index map (124 ring px in 128 slots)
__device__ __forceinline__ void ring_decode(int i, int& x, int& y) {
    if (i < 32)      { x = i;      y = 0;      }
    else if (i < 64) { x = i - 32; y = 31;     }
    else if (i < 94) { x = 0;      y = i - 63; }
    else             { x = 31;     y = i - 93; }
}

// Fused pass: blockIdx.x < 32 -> local CCL role; >= 32 -> stencil/moment role.
// Both roles use 256 threads; LDS is a shared carve (32.8 KB -> 4 blocks/CU).
__global__ void k_main(const float* __restrict__ dem, const float* __restrict__ pred,
                       float4* __restrict__ pmm, double* __restrict__ pblk,
                       int* __restrict__ pfg,
                       int* __restrict__ Lp, int* __restrict__ Cp,
                       int* __restrict__ nslot, int* __restrict__ pairmax,
                       int b0, int nloc, int featOn) {
    __shared__ double smem_d[4104];   // 32832 B
    int* smem = (int*)smem_d;
    const int tid = threadIdx.x;
    const int lane = tid & 63, wid = tid >> 6;

    if (blockIdx.x >= 32) {
        // ================= feat role =================
        if (!featOn) return;
        const int fb = blockIdx.x - 32;        // 0..127
        const int b = blockIdx.y;              // image
        const size_t off = (size_t)b * IMG_HW;
        const float* d = dem + off;
        const float* p = pred + off;
        const int base = fb * 2048 + tid * 8;  // wave == one full row
        const int y = base >> 9;

        const float4 z4 = make_float4(0.f, 0.f, 0.f, 0.f);
        float4 m0 = *(const float4*)(d + base);
        float4 m1 = *(const float4*)(d + base + 4);
        float4 u0 = z4, u1 = z4, w0 = z4, w1 = z4;
        if (y > 0)   { u0 = *(const float4*)(d + base - 512); u1 = *(const float4*)(d + base - 508); }
        if (y < 511) { w0 = *(const float4*)(d + base + 512); w1 = *(const float4*)(d + base + 516); }

        float uu[10], mm[10], ww[10];
        // halos from neighbor lanes (row == wave): 6 shuffles replace 6 loads
        { float t;
          t = __shfl(m1.w, lane - 1); mm[0] = (lane > 0)  ? t : 0.f;
          t = __shfl(m0.x, lane + 1); mm[9] = (lane < 63) ? t : 0.f;
          t = __shfl(u1.w, lane - 1); uu[0] = (lane > 0)  ? t : 0.f;
          t = __shfl(u0.x, lane + 1); uu[9] = (lane < 63) ? t : 0.f;
          t = __shfl(w1.w, lane - 1); ww[0] = (lane > 0)  ? t : 0.f;
          t = __shfl(w0.x, lane + 1); ww[9] = (lane < 63) ? t : 0.f; }
        uu[1]=u0.x; uu[2]=u0.y; uu[3]=u0.z; uu[4]=u0.w; uu[5]=u1.x; uu[6]=u1.y; uu[7]=u1.z; uu[8]=u1.w;
        mm[1]=m0.x; mm[2]=m0.y; mm[3]=m0.z; mm[4]=m0.w; mm[5]=m1.x; mm[6]=m1.y; mm[7]=m1.z; mm[8]=m1.w;
        ww[1]=w0.x; ww[2]=w0.y; ww[3]=w0.z; ww[4]=w0.w; ww[5]=w1.x; ww[6]=w1.y; ww[7]=w1.z; ww[8]=w1.w;

        const float4 p0 = *(const float4*)(p + base);
        const float4 p1 = *(const float4*)(p + base + 4);
        const float pv[8] = {p0.x, p0.y, p0.z, p0.w, p1.x, p1.y, p1.z, p1.w};

        float gmn = 3.4e38f, gmx = -3.4e38f, dmn = 3.4e38f, dmx = -3.4e38f;
        float mf[NMOM];
#pragma unroll
        for (int m = 0; m < NMOM; ++m) mf[m] = 0.f;
        int fg = 0;
#pragma unroll
        for (int j = 0; j < 8; ++j) {
            const float gx = (uu[j+2] - uu[j]) + 2.f * (mm[j+2] - mm[j]) + (ww[j+2] - ww[j]);
            const float gy = (ww[j] - uu[j]) + 2.f * (ww[j+1] - uu[j+1]) + (ww[j+2] - uu[j+2]);
            const float gm = sqrtf(gx * gx + gy * gy + 1e-8f);
            const float lap = uu[j+1] + mm[j] + mm[j+2] + ww[j+1] - 4.f * mm[j+1];
            const float cv = tanhf(lap * 0.1f);
            const float pj = pv[j], dj = mm[j+1];
            gmn = fminf(gmn, gm); gmx = fmaxf(gmx, gm);
            dmn = fminf(dmn, dj); dmx = fmaxf(dmx, dj);
            fg += (pj > 0.5f) ? 1 : 0;
            const float et = pj - cv;
            mf[0] += pj;  mf[1] += pj * pj;
            mf[2] += gm;  mf[3] += gm * gm;  mf[4] += pj * gm;
            mf[5] += dj;  mf[6] += dj * dj;  mf[7] += pj * dj;
            mf[8] += et * et;
        }

        for (int o = 32; o > 0; o >>= 1) {
            gmn = fminf(gmn, __shfl_down(gmn, o));
            gmx = fmaxf(gmx, __shfl_down(gmx, o));
            dmn = fminf(dmn, __shfl_down(dmn, o));
            dmx = fmaxf(dmx, __shfl_down(dmx, o));
#pragma unroll
            for (int m = 0; m < NMOM; ++m) mf[m] += __shfl_down(mf[m], o);
            fg += __shfl_down(fg, o);
        }
        // LDS carve: sa (4x9 f64), then 16 floats, then 4 ints
        double (*sa)[NMOM] = (double(*)[NMOM])smem_d;
        float* sg0 = (float*)(smem_d + 36);
        float* sg1 = sg0 + 4; float* sd0 = sg0 + 8; float* sd1 = sg0 + 12;
        int* sf = (int*)(sg0 + 16);
        if (lane == 0) {
            sg0[wid] = gmn; sg1[wid] = gmx; sd0[wid] = dmn; sd1[wid] = dmx; sf[wid] = fg;
#pragma unroll
            for (int m = 0; m < NMOM; ++m) sa[wid][m] = (double)mf[m];
        }
        __syncthreads();
        if (tid == 0) {
            double mo[NMOM];
#pragma unroll
            for (int m = 0; m < NMOM; ++m) mo[m] = sa[0][m];
            for (int w = 1; w < 4; ++w) {
                gmn = fminf(gmn, sg0[w]); gmx = fmaxf(gmx, sg1[w]);
                dmn = fminf(dmn, sd0[w]); dmx = fmaxf(dmx, sd1[w]);
                fg += sf[w];
#pragma unroll
                for (int m = 0; m < NMOM; ++m) mo[m] += sa[w][m];
            }
            const int bid = b * 128 + fb;
            pmm[bid] = make_float4(gmn, gmx, dmn, dmx);
#pragma unroll
            for (int m = 0; m < NMOM; ++m) pblk[(size_t)bid * NMOM + m] = mo[m];
            pfg[bid] = fg;
        }
        return;
    }

    // ================= local CCL role =================
    if (blockIdx.y >= nloc) return;
    const int slot = blockIdx.y;
    const float* p = pred + (size_t)(b0 + slot) * IMG_HW;
    int* L = Lp + (size_t)slot * NODES_PER_IMG;
    int* C = Cp + (size_t)slot * NODES_PER_IMG;
    const int pair = blockIdx.x * 4 + wid;      // 0..127
    const int tile0 = pair * 2;
    const int half = lane >> 5;
    const int tile = tile0 + half;
    const int tx0 = (tile0 & 15) * 32;          // 64-wide strip origin
    const int ty  = (tile0 >> 4) * 32;
    const int r = lane & 31;

    int* lab  = smem;            // 4x1024
    int* lcnt = smem + 4096;     // 4x1024
    int* ns   = smem + 8192;     // 4x2
    int* labw = lab + wid * 1024;
    int* lcw  = lcnt + wid * 1024;
    int* nsw  = ns + wid * 2;
    if (lane < 2) nsw[lane] = 0;
    const int nbase = half * 512;

    // Phase A: 8 float4 loads + 4 ballots each; reassemble my row mask.
    const int myit = r >> 2;
    unsigned long long q0 = 0, q1 = 0, q2 = 0, q3 = 0;
    for (int it = 0; it < 8; ++it) {
        const int row = it * 4 + (lane >> 4);
        const float4 v = *(const float4*)(p + (ty + row) * IMG_W + tx0 + (lane & 15) * 4);
        const unsigned long long t0 = __ballot(v.x > 0.5f);
        const unsigned long long t1 = __ballot(v.y > 0.5f);
        const unsigned long long t2 = __ballot(v.z > 0.5f);
        const unsigned long long t3 = __ballot(v.w > 0.5f);
        if (it == myit) { q0 = t0; q1 = t1; q2 = t2; q3 = t3; }
    }
#pragma unroll
    for (int k = 0; k < 16; ++k) {
        const int n = k * 64 + lane;
        labw[n] = n; lcw[n] = 0;
    }
    const int sh = 16 * (r & 3) + 8 * half;
    const unsigned m = spread4((unsigned)(q0 >> sh))
                     | (spread4((unsigned)(q1 >> sh)) << 1)
                     | (spread4((unsigned)(q2 >> sh)) << 2)
                     | (spread4((unsigned)(q3 >> sh)) << 3);
    const int mpl = __shfl((int)m, lane - 1);
    const unsigned mp = (r >= 1) ? (unsigned)mpl : 0u;

    const unsigned sm  = m  & ~(m << 1);
    const unsigned smp = mp & ~(mp << 1);

    // Phase B: vertical merges between overlapping runs of rows r-1, r.
    if (r >= 1) {
        unsigned ov = m & mp;
        while (ov) {
            const int bpos = __builtin_ctz(ov);
            const int sa2 = run_start(m, bpos);
            const int ea = sa2 + run_len(m, sa2) - 1;
            const int sb = run_start(mp, bpos);
            const int eb = sb + run_len(mp, sb) - 1;
            uf_merge(labw, nbase + run_idx(sm, sa2) * 32 + r,
                            nbase + run_idx(smp, sb) * 32 + (r - 1));
            const int e = (ea < eb) ? ea : eb;
            ov = (e >= 31) ? 0u : (ov & ~((1u << (e + 1)) - 1u));
        }
    }

    // Phase C: per-run sizes + boundary TOUCH + path compression.
    {
        unsigned rs = sm; int j = 0;
        while (rs) {
            const int st = __builtin_ctz(rs); rs &= rs - 1;
            const int len = run_len(m, st);
            const int e = st + len - 1;
            const int node = nbase + j * 32 + r; ++j;
            const int root = uf_findv(labw, node);
            if (root != node) labw[node] = root;
            atomicAdd(&lcw[root], len);
            if (r == 0 || r == 31 || st == 0 || e == 31)
                atomicOr(&lcw[root], TOUCH);
        }
    }

    // Phase D: interior roots -> locmax; boundary roots -> emit packed node.
    int locmax = 0;
    {
        unsigned rs = sm; int j = 0;
        while (rs) {
            rs &= rs - 1;
            const int node = nbase + j * 32 + r; ++j;
            if (labw[node] != node) continue;
            const int c = lcw[node];
            if (c & TOUCH) {
                const int sl = atomicAdd(&nsw[half], 1);
                const int gn = tile * NODES_PER_TILE + 128 + sl;
                L[gn] = gn;
                C[gn] = c & ~TOUCH;
                lcw[node] = gn;       // root -> packed id map
            } else {
                locmax = max(locmax, c);
            }
        }
    }
    for (int o = 32; o > 0; o >>= 1) locmax = max(locmax, __shfl_down(locmax, o));

    // Ring phase: 124 entries per tile x 2 tiles.
#pragma unroll
    for (int t = 0; t < 4; ++t) {
        const int i = lane + t * 64;           // 0..255
        const int h = i >> 7, idx = i & 127;
        const int tb = (tile0 + h) * NODES_PER_TILE;
        if (idx < 124) {
            int x, yy;
            ring_decode(idx, x, yy);
            const unsigned my = (unsigned)__shfl((int)m, h * 32 + yy);
            int val = -1;
            if ((my >> x) & 1u) {
                const unsigned smy = my & ~(my << 1);
                const int node = h * 512 + run_idx(smy, x) * 32 + yy;
                const int root = uf_findv(labw, node);
                val = lcw[root];
            }
            L[tb + idx] = val;
        } else {
            L[tb + idx] = -1;
        }
    }

    if (lane == 0) pairmax[slot * PAIRS + pair] = locmax;   // plain store
    if (lane < 2) nslot[slot * TILES + tile0 + lane] = nsw[lane];
}

// Stage-2 reduce. grid (IMG_B + 1 + NMOM).
__global__ void k_red(const float4* __restrict__ pmm, const double* __restrict__ pblk,
                      const int* __restrict__ pfg, Scal* s) {
    const int wid = threadIdx.x >> 6, lane = threadIdx.x & 63;
    if (blockIdx.x < IMG_B) {
        const int b = blockIdx.x;
        double ar = 0.0; int fg = 0;
        if (threadIdx.x < 128) {
            const int k = b * 128 + threadIdx.x;
            ar = pblk[(size_t)k * NMOM + 0];
            fg = pfg[k];
        }
        for (int o = 32; o > 0; o >>= 1) { ar += __shfl_down(ar, o); fg += __shfl_down(fg, o); }
        __shared__ double sa[4];
        __shared__ int sf[4];
        if (lane == 0) { sa[wid] = ar; sf[wid] = fg; }
        __syncthreads();
        if (threadIdx.x == 0) {
            ar += sa[1]; fg += sf[1];
            s->area[b] = ar; s->fgcnt[b] = fg;
        }
    } else if (blockIdx.x == IMG_B) {
        float gmn = 3.4e38f, gmx = -3.4e38f, dmn = 3.4e38f, dmx = -3.4e38f;
        for (int k = threadIdx.x; k < NPART; k += 256) {
            const float4 v = pmm[k];
            gmn = fminf(gmn, v.x); gmx = fmaxf(gmx, v.y);
            dmn = fminf(dmn, v.z); dmx = fmaxf(dmx, v.w);
        }
        for (int o = 32; o > 0; o >>= 1) {
            gmn = fminf(gmn, __shfl_down(gmn, o));
            gmx = fmaxf(gmx, __shfl_down(gmx, o));
            dmn = fminf(dmn, __shfl_down(dmn, o));
            dmx = fmaxf(dmx, __shfl_down(dmx, o));
        }
        __shared__ float sg0[4], sg1[4], sd0[4], sd1[4];
        if (lane == 0) { sg0[wid] = gmn; sg1[wid] = gmx; sd0[wid] = dmn; sd1[wid] = dmx; }
        __syncthreads();
        if (threadIdx.x == 0) {
            for (int w = 1; w < 4; ++w) {
                gmn = fminf(gmn, sg0[w]); gmx = fmaxf(gmx, sg1[w]);
                dmn = fminf(dmn, sd0[w]); dmx = fmaxf(dmx, sd1[w]);
            }
            s->gmin = gmn; s->gmax = gmx; s->dmin = dmn; s->dmax = dmx;
        }
    } else {
        const int m = blockIdx.x - IMG_B - 1;   // 0..NMOM-1
        double acc = 0.0;
        for (int k = threadIdx.x; k < NPART; k += 256) acc += pblk[(size_t)k * NMOM + m];
        for (int o = 32; o > 0; o >>= 1) acc += __shfl_down(acc, o);
        __shared__ double sa[4];
        if (lane == 0) sa[wid] = acc;
        __syncthreads();
        if (threadIdx.x == 0) {
            for (int w = 1; w < 4; ++w) acc += sa[w];
            s->mom[m] = acc;
        }
    }
}

// Fused seam-merge + flush + max: one 1024-thread block per image.
__global__ void k_graph(int* __restrict__ Lp, int* __restrict__ Cp,
                        const int* __restrict__ nslot, const int* __restrict__ pairmax,
                        Scal* s, int b0) {
    const int slot = blockIdx.x;
    int* L = Lp + (size_t)slot * NODES_PER_IMG;
    int* C = Cp + (size_t)slot * NODES_PER_IMG;
    const int tid = threadIdx.x;

    for (int e = tid; e < 15360; e += 1024) {
        int a, b;
        if (e < 7680) {             // vertical seam
            const int sc = e / 512, y = e - sc * 512;
            const int ly = y & 31;
            const int tL = (y >> 5) * 16 + sc;
            const int iL = (ly == 0) ? 31 : (ly == 31) ? 63 : (93 + ly);
            const int iR = (ly == 0) ? 0  : (ly == 31) ? 32 : (63 + ly);
            a = tL * NODES_PER_TILE + iL;
            b = (tL + 1) * NODES_PER_TILE + iR;
        } else {                    // horizontal seam
            const int e2 = e - 7680;
            const int sr = e2 / 512, x = e2 - sr * 512;
            const int lx = x & 31;
            const int tT = sr * 16 + (x >> 5);
            a = tT * NODES_PER_TILE + 32 + lx;
            b = (tT + 16) * NODES_PER_TILE + lx;
        }
        if (L[a] >= 0 && L[b] >= 0) uf_merge(L, a, b);
    }
    __syncthreads();

    for (int sidx = tid; sidx < TILES * 64; sidx += 1024) {
        const int tile = sidx >> 6, sl = sidx & 63;
        if (sl < nslot[slot * TILES + tile]) {
            const int g = tile * NODES_PER_TILE + 128 + sl;
            const int rt = uf_findv(L, g);
            if (rt != g) atomicAdd(&C[rt], C[g]);
        }
    }
    __syncthreads();

    int m = 0;
    for (int sidx = tid; sidx < TILES * 64; sidx += 1024) {
        const int tile = sidx >> 6, sl = sidx & 63;
        if (sl < nslot[slot * TILES + tile]) {
            const int g = tile * NODES_PER_TILE + 128 + sl;
            if (L[g] == g) m = max(m, C[g]);
        }
    }
    if (tid < PAIRS) m = max(m, pairmax[slot * PAIRS + tid]);
    for (int o = 32; o > 0; o >>= 1) m = max(m, __shfl_down(m, o));
    __shared__ int smx[16];
    const int wid = tid >> 6, lane = tid & 63;
    if (lane == 0) smx[wid] = m;
    __syncthreads();
    if (tid == 0) {
        for (int w = 1; w < 16; ++w) m = max(m, smx[w]);
        s->maxcnt[b0 + slot] = m;      // sole writer, plain store
    }
}

// Final: closed-form similarity from moments + conn + scale. 1 thread.
__global__ void k_final(const Scal* __restrict__ s, float* __restrict__ out) {
    const double N = (double)IMG_B * (double)IMG_HW;
    const float gdenf = s->gmax - s->gmin + 1e-8f;
    const float ddenf = s->dmax - s->dmin + 1e-8f;
    const double a = 1.0 / (double)gdenf, bb = 1.0 / (double)ddenf;
    const double gmin = (double)s->gmin, dmin = (double)s->dmin;
    const double S_p = s->mom[0], S_pp = s->mom[1];
    const double S_g = s->mom[2], S_gg = s->mom[3], S_pg = s->mom[4];
    const double S_d = s->mom[5], S_dd = s->mom[6], S_pd = s->mom[7];
    const double S_t = s->mom[8];
    const double sum_g = S_pp - 2.0 * a * (S_pg - gmin * S_p)
                       + a * a * (S_gg - 2.0 * gmin * S_g + gmin * gmin * N);
    const double sum_d = S_pp - 2.0 * bb * (S_pd - dmin * S_p)
                       + bb * bb * (S_dd - 2.0 * dmin * S_d + dmin * dmin * N);
    const double sim = (sum_g + sum_d + S_t) / (3.0 * N);

    const double tp = (double)IMG_HW;
    const double tmin = 0.1 * tp, tmax = 0.3 * tp;
    double conn = 0.0, scale = 0.0;
    for (int b = 0; b < IMG_B; ++b) {
        const int total = s->fgcnt[b];
        if (total > 0) conn += 1.0 - (double)s->maxcnt[b] / (double)total;
        const double ar = s->area[b];
        scale += fmax(ar - tmax, 0.0) + fmax(tmin - ar, 0.0);
    }
    conn /= (double)IMG_B;
    scale = (scale / (double)IMG_B) / tp;
    const double total = sim + 0.1 * conn + 0.05 * scale;
    out[0] = (float)(0.1 * total);
}

extern "C" void kernel_launch(void* const* d_in, const int* in_sizes, int n_in,
                              void* d_out, int out_size, void* d_ws, size_t ws_size,
                              hipStream_t stream) {
    const float* pred = (const float*)d_in[0];  // [16,1,512,512]
    const float* dem  = (const float*)d_in[1];  // [16,1,512,512]
    float* out = (float*)d_out;

    char* ws = (char*)d_ws;
    Scal* s = (Scal*)ws;
    float4* pmm  = (float4*)(ws + OFF_PMM);
    double* pblk = (double*)(ws + OFF_MOM);
    int*    pfg  = (int*)(ws + OFF_FG);
    int* scratch = (int*)(ws + OFF_SCR);
    const size_t avail_ints = (ws_size > OFF_SCR) ? (ws_size - OFF_SCR) / 4 : 0;
    const size_t per_img = 2ull * NODES_PER_IMG + TILES + PAIRS;

    long long chunk = (long long)(avail_ints / per_img);
    if (chunk < 1) chunk = 1;
    if (chunk > IMG_B) chunk = IMG_B;

    for (int b0 = 0; b0 < IMG_B; b0 += (int)chunk) {
        const int n = (int)((b0 + chunk <= IMG_B) ? chunk : (IMG_B - b0));
        int* Lp      = scratch;
        int* Cp      = scratch + (size_t)chunk * NODES_PER_IMG;
        int* nslotp  = scratch + 2ull * chunk * NODES_PER_IMG;
        int* pairmax = nslotp + (size_t)chunk * TILES;
        const int featOn = (b0 == 0) ? 1 : 0;
        const int gx = featOn ? 160 : 32;
        const int gy = featOn ? IMG_B : n;
        hipLaunchKernelGGL(k_main, dim3(gx, gy), dim3(256), 0, stream,
                           dem, pred, pmm, pblk, pfg, Lp, Cp, nslotp, pairmax,
                           b0, n, featOn);
        if (b0 == 0)
            hipLaunchKernelGGL(k_red, dim3(IMG_B + 1 + NMOM), dim3(256), 0, stream,
                               pmm, pblk, pfg, s);
        hipLaunchKernelGGL(k_graph, dim3(n), dim3(1024), 0, stream,
                           Lp, Cp, nslotp, pairmax, s, b0);
    }

    hipLaunchKernelGGL(k_final, dim3(1), dim3(1), 0, stream, s, out);
}

// Round 12
// 69.069 us; speedup vs baseline: 2.1802x; 2.1802x over previous
//
#include <hip/hip_runtime.h>
#include <math.h>

#define IMG_B 16
#define IMG_H 512
#define IMG_W 512
#define IMG_HW (IMG_H * IMG_W)
#define NPART 2048            // 128 feat blocks/image * 16 images

// moment indices: 0:S_p 1:S_pp 2:S_g 3:S_gg 4:S_pg 5:S_d 6:S_dd 7:S_pd 8:S_t
#define NMOM 9

// 32x32 tile CCL, packed boundary graph: per tile 192 nodes
//   slots 0..127  : ring pixels (ring index map below)
//   slots 128..191: boundary-component roots (compacted)
#define TILES 256             // per image (16x16)
#define NODES_PER_TILE 192
#define NODES_PER_IMG (TILES * NODES_PER_TILE)   // 49152
#define PAIRS 128             // tile pairs per image
#define TOUCH (1 << 30)

struct Scal {
    float gmin, gmax, dmin, dmax;
    double mom[NMOM];
    double area[IMG_B];
    int fgcnt[IMG_B];
    int maxcnt[IMG_B];
};

// ws layout (bytes):
//   0       Scal (padded to 512)
//   512     float4 pmm[NPART]            (32768)
//   33280   double pblk[NPART][NMOM]     (147456)
//   180736  int    pfg[NPART]            (8192)
//   188928  scratch: packed labels / counts / nslot / pairmax
#define OFF_PMM   512
#define OFF_MOM   33280
#define OFF_FG    180736
#define OFF_SCR   188928

// ---- union-find (LDS or global) ----
__device__ __forceinline__ int uf_findv(const int* L, int p) {
    while (true) { const int q = ((volatile const int*)L)[p]; if (q == p) return p; p = q; }
}
__device__ __forceinline__ void uf_merge(int* L, int a, int b) {
    while (true) {
        a = uf_findv(L, a);
        b = uf_findv(L, b);
        if (a == b) return;
        if (a < b) { int t = a; a = b; b = t; }
        const int old = atomicMin(&L[a], b);
        if (old == a) return;
        a = old;
    }
}

// ---- run bit helpers ----
__device__ __forceinline__ int run_start(unsigned m, int b) {
    const unsigned below = ~m & ((b == 0) ? 0u : ((1u << b) - 1u));
    return below ? (int)(32u - (unsigned)__builtin_clz(below)) : 0;
}
__device__ __forceinline__ int run_len(unsigned m, int s) {
    const unsigned inv = ~(m >> s);
    return inv ? __builtin_ctz(inv) : (32 - s);
}
__device__ __forceinline__ int run_idx(unsigned sm, int c) {
    return __popc(sm & (unsigned)((2ull << c) - 1ull)) - 1;
}
// spread 8 bits to stride-4 positions (bit i -> bit 4i)
__device__ __forceinline__ unsigned spread4(unsigned x) {
    x &= 0xFFu;
    x = (x | (x << 12)) & 0x000F000Fu;
    x = (x | (x << 6))  & 0x03030303u;
    x = (x | (x << 3))  & 0x11111111u;
    return x;
}

// ring index map (124 ring px in 128 slots)
__device__ __forceinline__ void ring_decode(int i, int& x, int& y) {
    if (i < 32)      { x = i;      y = 0;      }
    else if (i < 64) { x = i - 32; y = 31;     }
    else if (i < 94) { x = 0;      y = i - 63; }
    else             { x = 31;     y = i - 93; }
}

// Fused pass: blockIdx.x < 32 -> local CCL role; >= 32 -> stencil/moment role.
__global__ void k_main(const float* __restrict__ dem, const float* __restrict__ pred,
                       float4* __restrict__ pmm, double* __restrict__ pblk,
                       int* __restrict__ pfg,
                       int* __restrict__ Lp, int* __restrict__ Cp,
                       int* __restrict__ nslot, int* __restrict__ pairmax,
                       int b0, int nloc, int featOn) {
    __shared__ double smem_d[4104];   // 32832 B
    int* smem = (int*)smem_d;
    const int tid = threadIdx.x;
    const int lane = tid & 63, wid = tid >> 6;

    if (blockIdx.x >= 32) {
        // ================= feat role =================
        if (!featOn) return;
        const int fb = blockIdx.x - 32;        // 0..127
        const int b = blockIdx.y;              // image
        const size_t off = (size_t)b * IMG_HW;
        const float* d = dem + off;
        const float* p = pred + off;
        const int base = fb * 2048 + tid * 8;  // wave == one full row
        const int y = base >> 9;

        const float4 z4 = make_float4(0.f, 0.f, 0.f, 0.f);
        float4 m0 = *(const float4*)(d + base);
        float4 m1 = *(const float4*)(d + base + 4);
        float4 u0 = z4, u1 = z4, w0 = z4, w1 = z4;
        if (y > 0)   { u0 = *(const float4*)(d + base - 512); u1 = *(const float4*)(d + base - 508); }
        if (y < 511) { w0 = *(const float4*)(d + base + 512); w1 = *(const float4*)(d + base + 516); }

        float uu[10], mm[10], ww[10];
        { float t;
          t = __shfl(m1.w, lane - 1); mm[0] = (lane > 0)  ? t : 0.f;
          t = __shfl(m0.x, lane + 1); mm[9] = (lane < 63) ? t : 0.f;
          t = __shfl(u1.w, lane - 1); uu[0] = (lane > 0)  ? t : 0.f;
          t = __shfl(u0.x, lane + 1); uu[9] = (lane < 63) ? t : 0.f;
          t = __shfl(w1.w, lane - 1); ww[0] = (lane > 0)  ? t : 0.f;
          t = __shfl(w0.x, lane + 1); ww[9] = (lane < 63) ? t : 0.f; }
        uu[1]=u0.x; uu[2]=u0.y; uu[3]=u0.z; uu[4]=u0.w; uu[5]=u1.x; uu[6]=u1.y; uu[7]=u1.z; uu[8]=u1.w;
        mm[1]=m0.x; mm[2]=m0.y; mm[3]=m0.z; mm[4]=m0.w; mm[5]=m1.x; mm[6]=m1.y; mm[7]=m1.z; mm[8]=m1.w;
        ww[1]=w0.x; ww[2]=w0.y; ww[3]=w0.z; ww[4]=w0.w; ww[5]=w1.x; ww[6]=w1.y; ww[7]=w1.z; ww[8]=w1.w;

        const float4 p0 = *(const float4*)(p + base);
        const float4 p1 = *(const float4*)(p + base + 4);
        const float pv[8] = {p0.x, p0.y, p0.z, p0.w, p1.x, p1.y, p1.z, p1.w};

        float gmn = 3.4e38f, gmx = -3.4e38f, dmn = 3.4e38f, dmx = -3.4e38f;
        float mf[NMOM];
#pragma unroll
        for (int m = 0; m < NMOM; ++m) mf[m] = 0.f;
        int fg = 0;
#pragma unroll
        for (int j = 0; j < 8; ++j) {
            const float gx = (uu[j+2] - uu[j]) + 2.f * (mm[j+2] - mm[j]) + (ww[j+2] - ww[j]);
            const float gy = (ww[j] - uu[j]) + 2.f * (ww[j+1] - uu[j+1]) + (ww[j+2] - uu[j+2]);
            const float gm = sqrtf(gx * gx + gy * gy + 1e-8f);
            const float lap = uu[j+1] + mm[j] + mm[j+2] + ww[j+1] - 4.f * mm[j+1];
            const float cv = tanhf(lap * 0.1f);
            const float pj = pv[j], dj = mm[j+1];
            gmn = fminf(gmn, gm); gmx = fmaxf(gmx, gm);
            dmn = fminf(dmn, dj); dmx = fmaxf(dmx, dj);
            fg += (pj > 0.5f) ? 1 : 0;
            const float et = pj - cv;
            mf[0] += pj;  mf[1] += pj * pj;
            mf[2] += gm;  mf[3] += gm * gm;  mf[4] += pj * gm;
            mf[5] += dj;  mf[6] += dj * dj;  mf[7] += pj * dj;
            mf[8] += et * et;
        }

        for (int o = 32; o > 0; o >>= 1) {
            gmn = fminf(gmn, __shfl_down(gmn, o));
            gmx = fmaxf(gmx, __shfl_down(gmx, o));
            dmn = fminf(dmn, __shfl_down(dmn, o));
            dmx = fmaxf(dmx, __shfl_down(dmx, o));
#pragma unroll
            for (int m = 0; m < NMOM; ++m) mf[m] += __shfl_down(mf[m], o);
            fg += __shfl_down(fg, o);
        }
        double (*sa)[NMOM] = (double(*)[NMOM])smem_d;
        float* sg0 = (float*)(smem_d + 36);
        float* sg1 = sg0 + 4; float* sd0 = sg0 + 8; float* sd1 = sg0 + 12;
        int* sf = (int*)(sg0 + 16);
        if (lane == 0) {
            sg0[wid] = gmn; sg1[wid] = gmx; sd0[wid] = dmn; sd1[wid] = dmx; sf[wid] = fg;
#pragma unroll
            for (int m = 0; m < NMOM; ++m) sa[wid][m] = (double)mf[m];
        }
        __syncthreads();
        if (tid == 0) {
            double mo[NMOM];
#pragma unroll
            for (int m = 0; m < NMOM; ++m) mo[m] = sa[0][m];
            for (int w = 1; w < 4; ++w) {
                gmn = fminf(gmn, sg0[w]); gmx = fmaxf(gmx, sg1[w]);
                dmn = fminf(dmn, sd0[w]); dmx = fmaxf(dmx, sd1[w]);
                fg += sf[w];
#pragma unroll
                for (int m = 0; m < NMOM; ++m) mo[m] += sa[w][m];
            }
            const int bid = b * 128 + fb;
            pmm[bid] = make_float4(gmn, gmx, dmn, dmx);
#pragma unroll
            for (int m = 0; m < NMOM; ++m) pblk[(size_t)bid * NMOM + m] = mo[m];
            pfg[bid] = fg;
        }
        return;
    }

    // ================= local CCL role =================
    if (blockIdx.y >= nloc) return;
    const int slot = blockIdx.y;
    const float* p = pred + (size_t)(b0 + slot) * IMG_HW;
    int* L = Lp + (size_t)slot * NODES_PER_IMG;
    int* C = Cp + (size_t)slot * NODES_PER_IMG;
    const int pair = blockIdx.x * 4 + wid;      // 0..127
    const int tile0 = pair * 2;
    const int half = lane >> 5;
    const int tile = tile0 + half;
    const int tx0 = (tile0 & 15) * 32;          // 64-wide strip origin
    const int ty  = (tile0 >> 4) * 32;
    const int r = lane & 31;

    int* lab  = smem;            // 4x1024
    int* lcnt = smem + 4096;     // 4x1024
    int* ns   = smem + 8192;     // 4x2
    int* labw = lab + wid * 1024;
    int* lcw  = lcnt + wid * 1024;
    int* nsw  = ns + wid * 2;
    if (lane < 2) nsw[lane] = 0;
    const int nbase = half * 512;

    // Phase A: 8 float4 loads + 4 ballots each; reassemble my row mask.
    const int myit = r >> 2;
    unsigned long long q0 = 0, q1 = 0, q2 = 0, q3 = 0;
    for (int it = 0; it < 8; ++it) {
        const int row = it * 4 + (lane >> 4);
        const float4 v = *(const float4*)(p + (ty + row) * IMG_W + tx0 + (lane & 15) * 4);
        const unsigned long long t0 = __ballot(v.x > 0.5f);
        const unsigned long long t1 = __ballot(v.y > 0.5f);
        const unsigned long long t2 = __ballot(v.z > 0.5f);
        const unsigned long long t3 = __ballot(v.w > 0.5f);
        if (it == myit) { q0 = t0; q1 = t1; q2 = t2; q3 = t3; }
    }
#pragma unroll
    for (int k = 0; k < 16; ++k) {
        const int n = k * 64 + lane;
        labw[n] = n; lcw[n] = 0;
    }
    const int sh = 16 * (r & 3) + 8 * half;
    const unsigned m = spread4((unsigned)(q0 >> sh))
                     | (spread4((unsigned)(q1 >> sh)) << 1)
                     | (spread4((unsigned)(q2 >> sh)) << 2)
                     | (spread4((unsigned)(q3 >> sh)) << 3);
    const int mpl = __shfl((int)m, lane - 1);
    const unsigned mp = (r >= 1) ? (unsigned)mpl : 0u;

    const unsigned sm  = m  & ~(m << 1);
    const unsigned smp = mp & ~(mp << 1);

    // Phase B: vertical merges between overlapping runs of rows r-1, r.
    if (r >= 1) {
        unsigned ov = m & mp;
        while (ov) {
            const int bpos = __builtin_ctz(ov);
            const int sa2 = run_start(m, bpos);
            const int ea = sa2 + run_len(m, sa2) - 1;
            const int sb = run_start(mp, bpos);
            const int eb = sb + run_len(mp, sb) - 1;
            uf_merge(labw, nbase + run_idx(sm, sa2) * 32 + r,
                            nbase + run_idx(smp, sb) * 32 + (r - 1));
            const int e = (ea < eb) ? ea : eb;
            ov = (e >= 31) ? 0u : (ov & ~((1u << (e + 1)) - 1u));
        }
    }

    // Phase C: per-run sizes + boundary TOUCH + path compression.
    {
        unsigned rs = sm; int j = 0;
        while (rs) {
            const int st = __builtin_ctz(rs); rs &= rs - 1;
            const int len = run_len(m, st);
            const int e = st + len - 1;
            const int node = nbase + j * 32 + r; ++j;
            const int root = uf_findv(labw, node);
            if (root != node) labw[node] = root;
            atomicAdd(&lcw[root], len);
            if (r == 0 || r == 31 || st == 0 || e == 31)
                atomicOr(&lcw[root], TOUCH);
        }
    }

    // Phase D: interior roots -> locmax; boundary roots -> emit packed node.
    int locmax = 0;
    {
        unsigned rs = sm; int j = 0;
        while (rs) {
            rs &= rs - 1;
            const int node = nbase + j * 32 + r; ++j;
            if (labw[node] != node) continue;
            const int c = lcw[node];
            if (c & TOUCH) {
                const int sl = atomicAdd(&nsw[half], 1);
                const int gn = tile * NODES_PER_TILE + 128 + sl;
                L[gn] = gn;
                C[gn] = c & ~TOUCH;
                lcw[node] = gn;       // root -> packed id map
            } else {
                locmax = max(locmax, c);
            }
        }
    }
    for (int o = 32; o > 0; o >>= 1) locmax = max(locmax, __shfl_down(locmax, o));

    // Ring phase: 124 entries per tile x 2 tiles.
#pragma unroll
    for (int t = 0; t < 4; ++t) {
        const int i = lane + t * 64;           // 0..255
        const int h = i >> 7, idx = i & 127;
        const int tb = (tile0 + h) * NODES_PER_TILE;
        if (idx < 124) {
            int x, yy;
            ring_decode(idx, x, yy);
            const unsigned my = (unsigned)__shfl((int)m, h * 32 + yy);
            int val = -1;
            if ((my >> x) & 1u) {
                const unsigned smy = my & ~(my << 1);
                const int node = h * 512 + run_idx(smy, x) * 32 + yy;
                const int root = uf_findv(labw, node);
                val = lcw[root];
            }
            L[tb + idx] = val;
        } else {
            L[tb + idx] = -1;
        }
    }

    if (lane == 0) pairmax[slot * PAIRS + pair] = locmax;   // plain store
    if (lane < 2) nslot[slot * TILES + tile0 + lane] = nsw[lane];
}

// Stage-2 reduce; image blocks also init maxcnt=0 (runs before any k_lmax).
// grid (IMG_B + 1 + NMOM).
__global__ void k_red(const float4* __restrict__ pmm, const double* __restrict__ pblk,
                      const int* __restrict__ pfg, Scal* s) {
    const int wid = threadIdx.x >> 6, lane = threadIdx.x & 63;
    if (blockIdx.x < IMG_B) {
        const int b = blockIdx.x;
        double ar = 0.0; int fg = 0;
        if (threadIdx.x < 128) {
            const int k = b * 128 + threadIdx.x;
            ar = pblk[(size_t)k * NMOM + 0];
            fg = pfg[k];
        }
        for (int o = 32; o > 0; o >>= 1) { ar += __shfl_down(ar, o); fg += __shfl_down(fg, o); }
        __shared__ double sa[4];
        __shared__ int sf[4];
        if (lane == 0) { sa[wid] = ar; sf[wid] = fg; }
        __syncthreads();
        if (threadIdx.x == 0) {
            ar += sa[1]; fg += sf[1];
            s->area[b] = ar; s->fgcnt[b] = fg;
            s->maxcnt[b] = 0;
        }
    } else if (blockIdx.x == IMG_B) {
        float gmn = 3.4e38f, gmx = -3.4e38f, dmn = 3.4e38f, dmx = -3.4e38f;
        for (int k = threadIdx.x; k < NPART; k += 256) {
            const float4 v = pmm[k];
            gmn = fminf(gmn, v.x); gmx = fmaxf(gmx, v.y);
            dmn = fminf(dmn, v.z); dmx = fmaxf(dmx, v.w);
        }
        for (int o = 32; o > 0; o >>= 1) {
            gmn = fminf(gmn, __shfl_down(gmn, o));
            gmx = fmaxf(gmx, __shfl_down(gmx, o));
            dmn = fminf(dmn, __shfl_down(dmn, o));
            dmx = fmaxf(dmx, __shfl_down(dmx, o));
        }
        __shared__ float sg0[4], sg1[4], sd0[4], sd1[4];
        if (lane == 0) { sg0[wid] = gmn; sg1[wid] = gmx; sd0[wid] = dmn; sd1[wid] = dmx; }
        __syncthreads();
        if (threadIdx.x == 0) {
            for (int w = 1; w < 4; ++w) {
                gmn = fminf(gmn, sg0[w]); gmx = fmaxf(gmx, sg1[w]);
                dmn = fminf(dmn, sd0[w]); dmx = fmaxf(dmx, sd1[w]);
            }
            s->gmin = gmn; s->gmax = gmx; s->dmin = dmn; s->dmax = dmx;
        }
    } else {
        const int m = blockIdx.x - IMG_B - 1;   // 0..NMOM-1
        double acc = 0.0;
        for (int k = threadIdx.x; k < NPART; k += 256) acc += pblk[(size_t)k * NMOM + m];
        for (int o = 32; o > 0; o >>= 1) acc += __shfl_down(acc, o);
        __shared__ double sa[4];
        if (lane == 0) sa[wid] = acc;
        __syncthreads();
        if (threadIdx.x == 0) {
            for (int w = 1; w < 4; ++w) acc += sa[w];
            s->mom[m] = acc;
        }
    }
}

// Seam merges on the packed graph: 15360 edges/image, wide grid for latency
// hiding. grid (60, nimg), block 256.
__global__ void k_bmerge(int* __restrict__ Lp) {
    const int slot = blockIdx.y;
    int* L = Lp + (size_t)slot * NODES_PER_IMG;
    const int e = blockIdx.x * 256 + threadIdx.x;
    int a, b;
    if (e < 7680) {             // vertical seam sc (0..14), y (0..511)
        const int sc = e / 512, y = e - sc * 512;
        const int ly = y & 31;
        const int tL = (y >> 5) * 16 + sc;
        const int iL = (ly == 0) ? 31 : (ly == 31) ? 63 : (93 + ly);  // (31,ly)
        const int iR = (ly == 0) ? 0  : (ly == 31) ? 32 : (63 + ly);  // (0,ly)
        a = tL * NODES_PER_TILE + iL;
        b = (tL + 1) * NODES_PER_TILE + iR;
    } else {                    // horizontal seam sr (0..14), x (0..511)
        const int e2 = e - 7680;
        const int sr = e2 / 512, x = e2 - sr * 512;
        const int lx = x & 31;
        const int tT = sr * 16 + (x >> 5);
        a = tT * NODES_PER_TILE + 32 + lx;                 // (lx,31)
        b = (tT + 16) * NODES_PER_TILE + lx;               // (lx,0)
    }
    if (L[a] >= 0 && L[b] >= 0) uf_merge(L, a, b);
}

// Flush: listed roots push size to their global root. grid (64, nimg).
__global__ void k_lflush(const int* __restrict__ Lp, int* __restrict__ Cp,
                         const int* __restrict__ nslot) {
    const int img = blockIdx.y;
    const int* L = Lp + (size_t)img * NODES_PER_IMG;
    int* C = Cp + (size_t)img * NODES_PER_IMG;
    const int sidx = blockIdx.x * 256 + threadIdx.x;
    const int tile = sidx >> 6, sl = sidx & 63;
    if (sl >= nslot[img * TILES + tile]) return;
    const int g = tile * NODES_PER_TILE + 128 + sl;
    const int rt = uf_findv(L, g);
    if (rt != g) atomicAdd(&C[rt], C[g]);
}

// Max over global roots + pairmax. grid (65, nimg): block 64 handles pairmax.
__global__ void k_lmax(const int* __restrict__ Lp, const int* __restrict__ Cp,
                       const int* __restrict__ nslot, const int* __restrict__ pairmax,
                       Scal* s, int b0) {
    const int img = blockIdx.y;
    int m = 0;
    if (blockIdx.x < 64) {
        const int* L = Lp + (size_t)img * NODES_PER_IMG;
        const int* C = Cp + (size_t)img * NODES_PER_IMG;
        const int sidx = blockIdx.x * 256 + threadIdx.x;
        const int tile = sidx >> 6, sl = sidx & 63;
        if (sl < nslot[img * TILES + tile]) {
            const int g = tile * NODES_PER_TILE + 128 + sl;
            if (L[g] == g) m = C[g];
        }
    } else {
        if (threadIdx.x < PAIRS) m = pairmax[img * PAIRS + threadIdx.x];
    }
    for (int o = 32; o > 0; o >>= 1) m = max(m, __shfl_down(m, o));
    __shared__ int sm[4];
    const int wid = threadIdx.x >> 6, lane = threadIdx.x & 63;
    if (lane == 0) sm[wid] = m;
    __syncthreads();
    if (threadIdx.x == 0) {
        for (int w = 1; w < 4; ++w) m = max(m, sm[w]);
        if (m > 0) atomicMax(&s->maxcnt[b0 + img], m);
    }
}

// Final: closed-form similarity from moments + conn + scale. 1 thread.
__global__ void k_final(const Scal* __restrict__ s, float* __restrict__ out) {
    const double N = (double)IMG_B * (double)IMG_HW;
    const float gdenf = s->gmax - s->gmin + 1e-8f;
    const float ddenf = s->dmax - s->dmin + 1e-8f;
    const double a = 1.0 / (double)gdenf, bb = 1.0 / (double)ddenf;
    const double gmin = (double)s->gmin, dmin = (double)s->dmin;
    const double S_p = s->mom[0], S_pp = s->mom[1];
    const double S_g = s->mom[2], S_gg = s->mom[3], S_pg = s->mom[4];
    const double S_d = s->mom[5], S_dd = s->mom[6], S_pd = s->mom[7];
    const double S_t = s->mom[8];
    const double sum_g = S_pp - 2.0 * a * (S_pg - gmin * S_p)
                       + a * a * (S_gg - 2.0 * gmin * S_g + gmin * gmin * N);
    const double sum_d = S_pp - 2.0 * bb * (S_pd - dmin * S_p)
                       + bb * bb * (S_dd - 2.0 * dmin * S_d + dmin * dmin * N);
    const double sim = (sum_g + sum_d + S_t) / (3.0 * N);

    const double tp = (double)IMG_HW;
    const double tmin = 0.1 * tp, tmax = 0.3 * tp;
    double conn = 0.0, scale = 0.0;
    for (int b = 0; b < IMG_B; ++b) {
        const int total = s->fgcnt[b];
        if (total > 0) conn += 1.0 - (double)s->maxcnt[b] / (double)total;
        const double ar = s->area[b];
        scale += fmax(ar - tmax, 0.0) + fmax(tmin - ar, 0.0);
    }
    conn /= (double)IMG_B;
    scale = (scale / (double)IMG_B) / tp;
    const double total = sim + 0.1 * conn + 0.05 * scale;
    out[0] = (float)(0.1 * total);
}

extern "C" void kernel_launch(void* const* d_in, const int* in_sizes, int n_in,
                              void* d_out, int out_size, void* d_ws, size_t ws_size,
                              hipStream_t stream) {
    const float* pred = (const float*)d_in[0];  // [16,1,512,512]
    const float* dem  = (const float*)d_in[1];  // [16,1,512,512]
    float* out = (float*)d_out;

    char* ws = (char*)d_ws;
    Scal* s = (Scal*)ws;
    float4* pmm  = (float4*)(ws + OFF_PMM);
    double* pblk = (double*)(ws + OFF_MOM);
    int*    pfg  = (int*)(ws + OFF_FG);
    int* scratch = (int*)(ws + OFF_SCR);
    const size_t avail_ints = (ws_size > OFF_SCR) ? (ws_size - OFF_SCR) / 4 : 0;
    const size_t per_img = 2ull * NODES_PER_IMG + TILES + PAIRS;

    long long chunk = (long long)(avail_ints / per_img);
    if (chunk < 1) chunk = 1;
    if (chunk > IMG_B) chunk = IMG_B;

    for (int b0 = 0; b0 < IMG_B; b0 += (int)chunk) {
        const int n = (int)((b0 + chunk <= IMG_B) ? chunk : (IMG_B - b0));
        int* Lp      = scratch;
        int* Cp      = scratch + (size_t)chunk * NODES_PER_IMG;
        int* nslotp  = scratch + 2ull * chunk * NODES_PER_IMG;
        int* pairmax = nslotp + (size_t)chunk * TILES;
        const int featOn = (b0 == 0) ? 1 : 0;
        const int gx = featOn ? 160 : 32;
        const int gy = featOn ? IMG_B : n;
        hipLaunchKernelGGL(k_main, dim3(gx, gy), dim3(256), 0, stream,
                           dem, pred, pmm, pblk, pfg, Lp, Cp, nslotp, pairmax,
                           b0, n, featOn);
        if (b0 == 0)
            hipLaunchKernelGGL(k_red, dim3(IMG_B + 1 + NMOM), dim3(256), 0, stream,
                               pmm, pblk, pfg, s);
        hipLaunchKernelGGL(k_bmerge, dim3(60, n), dim3(256), 0, stream, Lp);
        hipLaunchKernelGGL(k_lflush, dim3(64, n), dim3(256), 0, stream, Lp, Cp, nslotp);
        hipLaunchKernelGGL(k_lmax,   dim3(65, n), dim3(256), 0, stream,
                           Lp, Cp, nslotp, pairmax, s, b0);
    }

    hipLaunchKernelGGL(k_final, dim3(1), dim3(1), 0, stream, s, out);
}

// Round 13
// 68.118 us; speedup vs baseline: 2.2106x; 1.0140x over previous
//
#include <hip/hip_runtime.h>
#include <math.h>

#define IMG_B 16
#define IMG_H 512
#define IMG_W 512
#define IMG_HW (IMG_H * IMG_W)
#define NPART 4096            // 256 feat blocks/image * 16 images

// moment indices: 0:S_p 1:S_pp 2:S_g 3:S_gg 4:S_pg 5:S_d 6:S_dd 7:S_pd 8:S_t
#define NMOM 9

// 32x32 tile CCL, packed boundary graph: per tile 192 nodes
#define TILES 256             // per image (16x16)
#define NODES_PER_TILE 192
#define NODES_PER_IMG (TILES * NODES_PER_TILE)   // 49152
#define PAIRS 128             // tile pairs per image
#define TOUCH (1 << 30)

struct Scal {
    float gmin, gmax, dmin, dmax;
    double mom[NMOM];
    double area[IMG_B];
    int fgcnt[IMG_B];
    int maxcnt[IMG_B];
};

// ws layout (bytes):
//   0       Scal (padded to 512)
//   512     float4 pmm[NPART]            (65536)
//   66048   double pblk[NPART][NMOM]     (294912)
//   360960  int    pfg[NPART]            (16384)
//   377344  scratch: packed labels / counts / nslot / pairmax
#define OFF_PMM   512
#define OFF_MOM   66048
#define OFF_FG    360960
#define OFF_SCR   377344

// ---- union-find (LDS or global) ----
__device__ __forceinline__ int uf_findv(const int* L, int p) {
    while (true) { const int q = ((volatile const int*)L)[p]; if (q == p) return p; p = q; }
}
__device__ __forceinline__ void uf_merge(int* L, int a, int b) {
    while (true) {
        a = uf_findv(L, a);
        b = uf_findv(L, b);
        if (a == b) return;
        if (a < b) { int t = a; a = b; b = t; }
        const int old = atomicMin(&L[a], b);
        if (old == a) return;
        a = old;
    }
}

// ---- run bit helpers ----
__device__ __forceinline__ int run_start(unsigned m, int b) {
    const unsigned below = ~m & ((b == 0) ? 0u : ((1u << b) - 1u));
    return below ? (int)(32u - (unsigned)__builtin_clz(below)) : 0;
}
__device__ __forceinline__ int run_len(unsigned m, int s) {
    const unsigned inv = ~(m >> s);
    return inv ? __builtin_ctz(inv) : (32 - s);
}
__device__ __forceinline__ int run_idx(unsigned sm, int c) {
    return __popc(sm & (unsigned)((2ull << c) - 1ull)) - 1;
}
// spread 8 bits to stride-4 positions (bit i -> bit 4i)
__device__ __forceinline__ unsigned spread4(unsigned x) {
    x &= 0xFFu;
    x = (x | (x << 12)) & 0x000F000Fu;
    x = (x | (x << 6))  & 0x03030303u;
    x = (x | (x << 3))  & 0x11111111u;
    return x;
}

// ring index map (124 ring px in 128 slots)
__device__ __forceinline__ void ring_decode(int i, int& x, int& y) {
    if (i < 32)      { x = i;      y = 0;      }
    else if (i < 64) { x = i - 32; y = 31;     }
    else if (i < 94) { x = 0;      y = i - 63; }
    else             { x = 31;     y = i - 93; }
}

// Fused pass, BLOCK = 128 (2 waves) for occupancy (LDS 16.4 KB -> ~9 blk/CU).
// blockIdx.x < 64 -> local CCL role (2 pairs/block); >= 64 -> feat role
// (2 rows/block, 256 blocks/image).
__global__ void k_main(const float* __restrict__ dem, const float* __restrict__ pred,
                       float4* __restrict__ pmm, double* __restrict__ pblk,
                       int* __restrict__ pfg,
                       int* __restrict__ Lp, int* __restrict__ Cp,
                       int* __restrict__ nslot, int* __restrict__ pairmax,
                       int b0, int nloc, int featOn) {
    __shared__ double smem_d[2052];   // 16416 B
    int* smem = (int*)smem_d;
    const int tid = threadIdx.x;
    const int lane = tid & 63, wid = tid >> 6;   // wid in {0,1}

    if (blockIdx.x >= 64) {
        // ================= feat role =================
        if (!featOn) return;
        const int fb = blockIdx.x - 64;        // 0..255
        const int b = blockIdx.y;              // image
        const size_t off = (size_t)b * IMG_HW;
        const float* d = dem + off;
        const float* p = pred + off;
        const int base = fb * 1024 + tid * 8;  // wave == one full row
        const int y = base >> 9;

        const float4 z4 = make_float4(0.f, 0.f, 0.f, 0.f);
        float4 m0 = *(const float4*)(d + base);
        float4 m1 = *(const float4*)(d + base + 4);
        float4 u0 = z4, u1 = z4, w0 = z4, w1 = z4;
        if (y > 0)   { u0 = *(const float4*)(d + base - 512); u1 = *(const float4*)(d + base - 508); }
        if (y < 511) { w0 = *(const float4*)(d + base + 512); w1 = *(const float4*)(d + base + 516); }

        float uu[10], mm[10], ww[10];
        { float t;
          t = __shfl(m1.w, lane - 1); mm[0] = (lane > 0)  ? t : 0.f;
          t = __shfl(m0.x, lane + 1); mm[9] = (lane < 63) ? t : 0.f;
          t = __shfl(u1.w, lane - 1); uu[0] = (lane > 0)  ? t : 0.f;
          t = __shfl(u0.x, lane + 1); uu[9] = (lane < 63) ? t : 0.f;
          t = __shfl(w1.w, lane - 1); ww[0] = (lane > 0)  ? t : 0.f;
          t = __shfl(w0.x, lane + 1); ww[9] = (lane < 63) ? t : 0.f; }
        uu[1]=u0.x; uu[2]=u0.y; uu[3]=u0.z; uu[4]=u0.w; uu[5]=u1.x; uu[6]=u1.y; uu[7]=u1.z; uu[8]=u1.w;
        mm[1]=m0.x; mm[2]=m0.y; mm[3]=m0.z; mm[4]=m0.w; mm[5]=m1.x; mm[6]=m1.y; mm[7]=m1.z; mm[8]=m1.w;
        ww[1]=w0.x; ww[2]=w0.y; ww[3]=w0.z; ww[4]=w0.w; ww[5]=w1.x; ww[6]=w1.y; ww[7]=w1.z; ww[8]=w1.w;

        const float4 p0 = *(const float4*)(p + base);
        const float4 p1 = *(const float4*)(p + base + 4);
        const float pv[8] = {p0.x, p0.y, p0.z, p0.w, p1.x, p1.y, p1.z, p1.w};

        float gmn = 3.4e38f, gmx = -3.4e38f, dmn = 3.4e38f, dmx = -3.4e38f;
        float mf[NMOM];
#pragma unroll
        for (int m = 0; m < NMOM; ++m) mf[m] = 0.f;
        int fg = 0;
#pragma unroll
        for (int j = 0; j < 8; ++j) {
            const float gx = (uu[j+2] - uu[j]) + 2.f * (mm[j+2] - mm[j]) + (ww[j+2] - ww[j]);
            const float gy = (ww[j] - uu[j]) + 2.f * (ww[j+1] - uu[j+1]) + (ww[j+2] - uu[j+2]);
            const float gm = sqrtf(gx * gx + gy * gy + 1e-8f);
            const float lap = uu[j+1] + mm[j] + mm[j+2] + ww[j+1] - 4.f * mm[j+1];
            const float cv = tanhf(lap * 0.1f);
            const float pj = pv[j], dj = mm[j+1];
            gmn = fminf(gmn, gm); gmx = fmaxf(gmx, gm);
            dmn = fminf(dmn, dj); dmx = fmaxf(dmx, dj);
            fg += (pj > 0.5f) ? 1 : 0;
            const float et = pj - cv;
            mf[0] += pj;  mf[1] += pj * pj;
            mf[2] += gm;  mf[3] += gm * gm;  mf[4] += pj * gm;
            mf[5] += dj;  mf[6] += dj * dj;  mf[7] += pj * dj;
            mf[8] += et * et;
        }

        for (int o = 32; o > 0; o >>= 1) {
            gmn = fminf(gmn, __shfl_down(gmn, o));
            gmx = fmaxf(gmx, __shfl_down(gmx, o));
            dmn = fminf(dmn, __shfl_down(dmn, o));
            dmx = fmaxf(dmx, __shfl_down(dmx, o));
#pragma unroll
            for (int m = 0; m < NMOM; ++m) mf[m] += __shfl_down(mf[m], o);
            fg += __shfl_down(fg, o);
        }
        double (*sa)[NMOM] = (double(*)[NMOM])smem_d;     // 2x9 doubles
        float* sg0 = (float*)(smem_d + 18);
        float* sg1 = sg0 + 2; float* sd0 = sg0 + 4; float* sd1 = sg0 + 6;
        int* sf = (int*)(sg0 + 8);
        if (lane == 0) {
            sg0[wid] = gmn; sg1[wid] = gmx; sd0[wid] = dmn; sd1[wid] = dmx; sf[wid] = fg;
#pragma unroll
            for (int m = 0; m < NMOM; ++m) sa[wid][m] = (double)mf[m];
        }
        __syncthreads();
        if (tid == 0) {
            double mo[NMOM];
#pragma unroll
            for (int m = 0; m < NMOM; ++m) mo[m] = sa[0][m] + sa[1][m];
            gmn = fminf(gmn, sg0[1]); gmx = fmaxf(gmx, sg1[1]);
            dmn = fminf(dmn, sd0[1]); dmx = fmaxf(dmx, sd1[1]);
            fg += sf[1];
            const int bid = b * 256 + fb;
            pmm[bid] = make_float4(gmn, gmx, dmn, dmx);
#pragma unroll
            for (int m = 0; m < NMOM; ++m) pblk[(size_t)bid * NMOM + m] = mo[m];
            pfg[bid] = fg;
        }
        return;
    }

    // ================= local CCL role =================
    if (blockIdx.y >= nloc) return;
    const int slot = blockIdx.y;
    const float* p = pred + (size_t)(b0 + slot) * IMG_HW;
    int* L = Lp + (size_t)slot * NODES_PER_IMG;
    int* C = Cp + (size_t)slot * NODES_PER_IMG;
    const int pair = blockIdx.x * 2 + wid;      // 0..127
    const int tile0 = pair * 2;
    const int half = lane >> 5;
    const int tile = tile0 + half;
    const int tx0 = (tile0 & 15) * 32;          // 64-wide strip origin
    const int ty  = (tile0 >> 4) * 32;
    const int r = lane & 31;

    int* lab  = smem;            // 2x1024
    int* lcnt = smem + 2048;     // 2x1024
    int* ns   = smem + 4096;     // 2x2
    int* labw = lab + wid * 1024;
    int* lcw  = lcnt + wid * 1024;
    int* nsw  = ns + wid * 2;
    if (lane < 2) nsw[lane] = 0;
    const int nbase = half * 512;

    // Phase A: 8 float4 loads + 4 ballots each; reassemble my row mask.
    const int myit = r >> 2;
    unsigned long long q0 = 0, q1 = 0, q2 = 0, q3 = 0;
    for (int it = 0; it < 8; ++it) {
        const int row = it * 4 + (lane >> 4);
        const float4 v = *(const float4*)(p + (ty + row) * IMG_W + tx0 + (lane & 15) * 4);
        const unsigned long long t0 = __ballot(v.x > 0.5f);
        const unsigned long long t1 = __ballot(v.y > 0.5f);
        const unsigned long long t2 = __ballot(v.z > 0.5f);
        const unsigned long long t3 = __ballot(v.w > 0.5f);
        if (it == myit) { q0 = t0; q1 = t1; q2 = t2; q3 = t3; }
    }
#pragma unroll
    for (int k = 0; k < 16; ++k) {
        const int n = k * 64 + lane;
        labw[n] = n; lcw[n] = 0;
    }
    const int sh = 16 * (r & 3) + 8 * half;
    const unsigned m = spread4((unsigned)(q0 >> sh))
                     | (spread4((unsigned)(q1 >> sh)) << 1)
                     | (spread4((unsigned)(q2 >> sh)) << 2)
                     | (spread4((unsigned)(q3 >> sh)) << 3);
    const int mpl = __shfl((int)m, lane - 1);
    const unsigned mp = (r >= 1) ? (unsigned)mpl : 0u;

    const unsigned sm  = m  & ~(m << 1);
    const unsigned smp = mp & ~(mp << 1);

    // Phase B: vertical merges between overlapping runs of rows r-1, r.
    if (r >= 1) {
        unsigned ov = m & mp;
        while (ov) {
            const int bpos = __builtin_ctz(ov);
            const int sa2 = run_start(m, bpos);
            const int ea = sa2 + run_len(m, sa2) - 1;
            const int sb = run_start(mp, bpos);
            const int eb = sb + run_len(mp, sb) - 1;
            uf_merge(labw, nbase + run_idx(sm, sa2) * 32 + r,
                            nbase + run_idx(smp, sb) * 32 + (r - 1));
            const int e = (ea < eb) ? ea : eb;
            ov = (e >= 31) ? 0u : (ov & ~((1u << (e + 1)) - 1u));
        }
    }

    // Phase C: per-run sizes + boundary TOUCH + path compression.
    {
        unsigned rs = sm; int j = 0;
        while (rs) {
            const int st = __builtin_ctz(rs); rs &= rs - 1;
            const int len = run_len(m, st);
            const int e = st + len - 1;
            const int node = nbase + j * 32 + r; ++j;
            const int root = uf_findv(labw, node);
            if (root != node) labw[node] = root;
            atomicAdd(&lcw[root], len);
            if (r == 0 || r == 31 || st == 0 || e == 31)
                atomicOr(&lcw[root], TOUCH);
        }
    }

    // Phase D: interior roots -> locmax; boundary roots -> emit packed node.
    int locmax = 0;
    {
        unsigned rs = sm; int j = 0;
        while (rs) {
            rs &= rs - 1;
            const int node = nbase + j * 32 + r; ++j;
            if (labw[node] != node) continue;
            const int c = lcw[node];
            if (c & TOUCH) {
                const int sl = atomicAdd(&nsw[half], 1);
                const int gn = tile * NODES_PER_TILE + 128 + sl;
                L[gn] = gn;
                C[gn] = c & ~TOUCH;
                lcw[node] = gn;       // root -> packed id map
            } else {
                locmax = max(locmax, c);
            }
        }
    }
    for (int o = 32; o > 0; o >>= 1) locmax = max(locmax, __shfl_down(locmax, o));

    // Ring phase: 124 entries per tile x 2 tiles.
#pragma unroll
    for (int t = 0; t < 4; ++t) {
        const int i = lane + t * 64;           // 0..255
        const int h = i >> 7, idx = i & 127;
        const int tb = (tile0 + h) * NODES_PER_TILE;
        if (idx < 124) {
            int x, yy;
            ring_decode(idx, x, yy);
            const unsigned my = (unsigned)__shfl((int)m, h * 32 + yy);
            int val = -1;
            if ((my >> x) & 1u) {
                const unsigned smy = my & ~(my << 1);
                const int node = h * 512 + run_idx(smy, x) * 32 + yy;
                const int root = uf_findv(labw, node);
                val = lcw[root];
            }
            L[tb + idx] = val;
        } else {
            L[tb + idx] = -1;
        }
    }

    if (lane == 0) pairmax[slot * PAIRS + pair] = locmax;   // plain store
    if (lane < 2) nslot[slot * TILES + tile0 + lane] = nsw[lane];
}

// Stage-2 reduce; image blocks also init maxcnt=0 (runs before any k_tail).
// grid (IMG_B + 1 + NMOM), block 256.
__global__ void k_red(const float4* __restrict__ pmm, const double* __restrict__ pblk,
                      const int* __restrict__ pfg, Scal* s) {
    const int wid = threadIdx.x >> 6, lane = threadIdx.x & 63;
    if (blockIdx.x < IMG_B) {
        const int b = blockIdx.x;
        const int k = b * 256 + threadIdx.x;
        double ar = pblk[(size_t)k * NMOM + 0];
        int fg = pfg[k];
        for (int o = 32; o > 0; o >>= 1) { ar += __shfl_down(ar, o); fg += __shfl_down(fg, o); }
        __shared__ double sa[4];
        __shared__ int sf[4];
        if (lane == 0) { sa[wid] = ar; sf[wid] = fg; }
        __syncthreads();
        if (threadIdx.x == 0) {
            for (int w = 1; w < 4; ++w) { ar += sa[w]; fg += sf[w]; }
            s->area[b] = ar; s->fgcnt[b] = fg;
            s->maxcnt[b] = 0;
        }
    } else if (blockIdx.x == IMG_B) {
        float gmn = 3.4e38f, gmx = -3.4e38f, dmn = 3.4e38f, dmx = -3.4e38f;
        for (int k = threadIdx.x; k < NPART; k += 256) {
            const float4 v = pmm[k];
            gmn = fminf(gmn, v.x); gmx = fmaxf(gmx, v.y);
            dmn = fminf(dmn, v.z); dmx = fmaxf(dmx, v.w);
        }
        for (int o = 32; o > 0; o >>= 1) {
            gmn = fminf(gmn, __shfl_down(gmn, o));
            gmx = fmaxf(gmx, __shfl_down(gmx, o));
            dmn = fminf(dmn, __shfl_down(dmn, o));
            dmx = fmaxf(dmx, __shfl_down(dmx, o));
        }
        __shared__ float sg0[4], sg1[4], sd0[4], sd1[4];
        if (lane == 0) { sg0[wid] = gmn; sg1[wid] = gmx; sd0[wid] = dmn; sd1[wid] = dmx; }
        __syncthreads();
        if (threadIdx.x == 0) {
            for (int w = 1; w < 4; ++w) {
                gmn = fminf(gmn, sg0[w]); gmx = fmaxf(gmx, sg1[w]);
                dmn = fminf(dmn, sd0[w]); dmx = fmaxf(dmx, sd1[w]);
            }
            s->gmin = gmn; s->gmax = gmx; s->dmin = dmn; s->dmax = dmx;
        }
    } else {
        const int m = blockIdx.x - IMG_B - 1;   // 0..NMOM-1
        double acc = 0.0;
        for (int k = threadIdx.x; k < NPART; k += 256) acc += pblk[(size_t)k * NMOM + m];
        for (int o = 32; o > 0; o >>= 1) acc += __shfl_down(acc, o);
        __shared__ double sa[4];
        if (lane == 0) sa[wid] = acc;
        __syncthreads();
        if (threadIdx.x == 0) {
            for (int w = 1; w < 4; ++w) acc += sa[w];
            s->mom[m] = acc;
        }
    }
}

// Seam merges on the packed graph: 15360 edges/image, wide grid.
// grid (60, nimg), block 256.
__global__ void k_bmerge(int* __restrict__ Lp) {
    const int slot = blockIdx.y;
    int* L = Lp + (size_t)slot * NODES_PER_IMG;
    const int e = blockIdx.x * 256 + threadIdx.x;
    int a, b;
    if (e < 7680) {             // vertical seam sc (0..14), y (0..511)
        const int sc = e / 512, y = e - sc * 512;
        const int ly = y & 31;
        const int tL = (y >> 5) * 16 + sc;
        const int iL = (ly == 0) ? 31 : (ly == 31) ? 63 : (93 + ly);  // (31,ly)
        const int iR = (ly == 0) ? 0  : (ly == 31) ? 32 : (63 + ly);  // (0,ly)
        a = tL * NODES_PER_TILE + iL;
        b = (tL + 1) * NODES_PER_TILE + iR;
    } else {                    // horizontal seam sr (0..14), x (0..511)
        const int e2 = e - 7680;
        const int sr = e2 / 512, x = e2 - sr * 512;
        const int lx = x & 31;
        const int tT = sr * 16 + (x >> 5);
        a = tT * NODES_PER_TILE + 32 + lx;                 // (lx,31)
        b = (tT + 16) * NODES_PER_TILE + lx;               // (lx,0)
    }
    if (L[a] >= 0 && L[b] >= 0) uf_merge(L, a, b);
}

// Fused flush+max: each listed root pushes size to its global root; the
// LAST adder's (old+sz) equals the component total (atomicAdd serializes),
// so max over all reports = max component size (deterministic). Roots
// report their own sz (exact when the component is single-tile, else a
// lower bound covered by the last adder). Block 64 folds pairmax.
// grid (65, nimg), block 256.
__global__ void k_tail(const int* __restrict__ Lp, int* __restrict__ Cp,
                       const int* __restrict__ nslot, const int* __restrict__ pairmax,
                       Scal* s, int b0) {
    const int img = blockIdx.y;
    int m = 0;
    if (blockIdx.x < 64) {
        const int* L = Lp + (size_t)img * NODES_PER_IMG;
        int* C = Cp + (size_t)img * NODES_PER_IMG;
        const int sidx = blockIdx.x * 256 + threadIdx.x;
        const int tile = sidx >> 6, sl = sidx & 63;
        if (sl < nslot[img * TILES + tile]) {
            const int g = tile * NODES_PER_TILE + 128 + sl;
            const int sz = C[g];
            const int rt = uf_findv(L, g);
            if (rt != g) m = atomicAdd(&C[rt], sz) + sz;
            else         m = sz;
        }
    } else {
        if (threadIdx.x < PAIRS) m = pairmax[img * PAIRS + threadIdx.x];
    }
    for (int o = 32; o > 0; o >>= 1) m = max(m, __shfl_down(m, o));
    __shared__ int sm[4];
    const int wid = threadIdx.x >> 6, lane = threadIdx.x & 63;
    if (lane == 0) sm[wid] = m;
    __syncthreads();
    if (threadIdx.x == 0) {
        for (int w = 1; w < 4; ++w) m = max(m, sm[w]);
        if (m > 0) atomicMax(&s->maxcnt[b0 + img], m);
    }
}

// Final: closed-form similarity from moments + conn + scale. 1 thread.
__global__ void k_final(const Scal* __restrict__ s, float* __restrict__ out) {
    const double N = (double)IMG_B * (double)IMG_HW;
    const float gdenf = s->gmax - s->gmin + 1e-8f;
    const float ddenf = s->dmax - s->dmin + 1e-8f;
    const double a = 1.0 / (double)gdenf, bb = 1.0 / (double)ddenf;
    const double gmin = (double)s->gmin, dmin = (double)s->dmin;
    const double S_p = s->mom[0], S_pp = s->mom[1];
    const double S_g = s->mom[2], S_gg = s->mom[3], S_pg = s->mom[4];
    const double S_d = s->mom[5], S_dd = s->mom[6], S_pd = s->mom[7];
    const double S_t = s->mom[8];
    const double sum_g = S_pp - 2.0 * a * (S_pg - gmin * S_p)
                       + a * a * (S_gg - 2.0 * gmin * S_g + gmin * gmin * N);
    const double sum_d = S_pp - 2.0 * bb * (S_pd - dmin * S_p)
                       + bb * bb * (S_dd - 2.0 * dmin * S_d + dmin * dmin * N);
    const double sim = (sum_g + sum_d + S_t) / (3.0 * N);

    const double tp = (double)IMG_HW;
    const double tmin = 0.1 * tp, tmax = 0.3 * tp;
    double conn = 0.0, scale = 0.0;
    for (int b = 0; b < IMG_B; ++b) {
        const int total = s->fgcnt[b];
        if (total > 0) conn += 1.0 - (double)s->maxcnt[b] / (double)total;
        const double ar = s->area[b];
        scale += fmax(ar - tmax, 0.0) + fmax(tmin - ar, 0.0);
    }
    conn /= (double)IMG_B;
    scale = (scale / (double)IMG_B) / tp;
    const double total = sim + 0.1 * conn + 0.05 * scale;
    out[0] = (float)(0.1 * total);
}

extern "C" void kernel_launch(void* const* d_in, const int* in_sizes, int n_in,
                              void* d_out, int out_size, void* d_ws, size_t ws_size,
                              hipStream_t stream) {
    const float* pred = (const float*)d_in[0];  // [16,1,512,512]
    const float* dem  = (const float*)d_in[1];  // [16,1,512,512]
    float* out = (float*)d_out;

    char* ws = (char*)d_ws;
    Scal* s = (Scal*)ws;
    float4* pmm  = (float4*)(ws + OFF_PMM);
    double* pblk = (double*)(ws + OFF_MOM);
    int*    pfg  = (int*)(ws + OFF_FG);
    int* scratch = (int*)(ws + OFF_SCR);
    const size_t avail_ints = (ws_size > OFF_SCR) ? (ws_size - OFF_SCR) / 4 : 0;
    const size_t per_img = 2ull * NODES_PER_IMG + TILES + PAIRS;

    long long chunk = (long long)(avail_ints / per_img);
    if (chunk < 1) chunk = 1;
    if (chunk > IMG_B) chunk = IMG_B;

    for (int b0 = 0; b0 < IMG_B; b0 += (int)chunk) {
        const int n = (int)((b0 + chunk <= IMG_B) ? chunk : (IMG_B - b0));
        int* Lp      = scratch;
        int* Cp      = scratch + (size_t)chunk * NODES_PER_IMG;
        int* nslotp  = scratch + 2ull * chunk * NODES_PER_IMG;
        int* pairmax = nslotp + (size_t)chunk * TILES;
        const int featOn = (b0 == 0) ? 1 : 0;
        const int gx = featOn ? 320 : 64;
        const int gy = featOn ? IMG_B : n;
        hipLaunchKernelGGL(k_main, dim3(gx, gy), dim3(128), 0, stream,
                           dem, pred, pmm, pblk, pfg, Lp, Cp, nslotp, pairmax,
                           b0, n, featOn);
        if (b0 == 0)
            hipLaunchKernelGGL(k_red, dim3(IMG_B + 1 + NMOM), dim3(256), 0, stream,
                               pmm, pblk, pfg, s);
        hipLaunchKernelGGL(k_bmerge, dim3(60, n), dim3(256), 0, stream, Lp);
        hipLaunchKernelGGL(k_tail,   dim3(65, n), dim3(256), 0, stream,
                           Lp, Cp, nslotp, pairmax, s, b0);
    }

    hipLaunchKernelGGL(k_final, dim3(1), dim3(1), 0, stream, s, out);
}

// Round 14
// 67.419 us; speedup vs baseline: 2.2335x; 1.0104x over previous
//
#include <hip/hip_runtime.h>
#include <math.h>

#define IMG_B 16
#define IMG_H 512
#define IMG_W 512
#define IMG_HW (IMG_H * IMG_W)
#define NPART 2048            // 128 feat blocks/image * 16 images

// moment indices: 0:S_p 1:S_pp 2:S_g 3:S_gg 4:S_pg 5:S_d 6:S_dd 7:S_pd 8:S_t
#define NMOM 9

// 32x32 tile CCL, packed boundary graph: per tile 192 nodes
#define TILES 256             // per image (16x16)
#define NODES_PER_TILE 192
#define NODES_PER_IMG (TILES * NODES_PER_TILE)   // 49152
#define PAIRS 128             // tile pairs per image
#define TOUCH (1 << 30)

struct Scal {
    float gmin, gmax, dmin, dmax;
    double mom[NMOM];
    double area[IMG_B];
    int fgcnt[IMG_B];
    int maxcnt[IMG_B];
};

// ws layout (bytes):
//   0       Scal (padded to 512)
//   512     float4 pmm[NPART]            (32768)
//   33280   double pblk[NPART][NMOM]     (147456)
//   180736  int    pfg[NPART]            (8192)
//   188928  scratch: packed labels / counts / nslot / pairmax
#define OFF_PMM   512
#define OFF_MOM   33280
#define OFF_FG    180736
#define OFF_SCR   188928

// ---- union-find (LDS or global) ----
__device__ __forceinline__ int uf_findv(const int* L, int p) {
    while (true) { const int q = ((volatile const int*)L)[p]; if (q == p) return p; p = q; }
}
__device__ __forceinline__ void uf_merge(int* L, int a, int b) {
    while (true) {
        a = uf_findv(L, a);
        b = uf_findv(L, b);
        if (a == b) return;
        if (a < b) { int t = a; a = b; b = t; }
        const int old = atomicMin(&L[a], b);
        if (old == a) return;
        a = old;
    }
}

// ---- run bit helpers ----
__device__ __forceinline__ int run_start(unsigned m, int b) {
    const unsigned below = ~m & ((b == 0) ? 0u : ((1u << b) - 1u));
    return below ? (int)(32u - (unsigned)__builtin_clz(below)) : 0;
}
__device__ __forceinline__ int run_len(unsigned m, int s) {
    const unsigned inv = ~(m >> s);
    return inv ? __builtin_ctz(inv) : (32 - s);
}
__device__ __forceinline__ int run_idx(unsigned sm, int c) {
    return __popc(sm & (unsigned)((2ull << c) - 1ull)) - 1;
}
// spread 8 bits to stride-4 positions (bit i -> bit 4i)
__device__ __forceinline__ unsigned spread4(unsigned x) {
    x &= 0xFFu;
    x = (x | (x << 12)) & 0x000F000Fu;
    x = (x | (x << 6))  & 0x03030303u;
    x = (x | (x << 3))  & 0x11111111u;
    return x;
}

// ring index map (124 ring px in 128 slots)
__device__ __forceinline__ void ring_decode(int i, int& x, int& y) {
    if (i < 32)      { x = i;      y = 0;      }
    else if (i < 64) { x = i - 32; y = 31;     }
    else if (i < 94) { x = 0;      y = i - 63; }
    else             { x = 31;     y = i - 93; }
}

// Fused pass, BLOCK = 128 (2 waves). blockIdx.x < 64 -> local CCL role
// (2 pairs/block); >= 64 -> feat role (16 px/thread, 4 rows/block,
// 128 blocks/image). Wave == 2 full rows -> halos via 6 shuffles.
__global__ void k_main(const float* __restrict__ dem, const float* __restrict__ pred,
                       float4* __restrict__ pmm, double* __restrict__ pblk,
                       int* __restrict__ pfg,
                       int* __restrict__ Lp, int* __restrict__ Cp,
                       int* __restrict__ nslot, int* __restrict__ pairmax,
                       int b0, int nloc, int featOn) {
    __shared__ double smem_d[2052];   // 16416 B
    int* smem = (int*)smem_d;
    const int tid = threadIdx.x;
    const int lane = tid & 63, wid = tid >> 6;   // wid in {0,1}

    if (blockIdx.x >= 64) {
        // ================= feat role: 16 px/thread =================
        if (!featOn) return;
        const int fb = blockIdx.x - 64;        // 0..127
        const int b = blockIdx.y;              // image
        const size_t off = (size_t)b * IMG_HW;
        const float* d = dem + off;
        const float* p = pred + off;
        const int base = fb * 2048 + tid * 16; // lane covers 16 px of one row
        const int y = base >> 9;
        const int xl = lane & 31;              // lane-within-row (0..31)

        float4 M[4], U[4], W[4], P[4];
        const float4 z4 = make_float4(0.f, 0.f, 0.f, 0.f);
#pragma unroll
        for (int k = 0; k < 4; ++k) {
            M[k] = *(const float4*)(d + base + 4 * k);
            U[k] = (y > 0)   ? *(const float4*)(d + base - 512 + 4 * k) : z4;
            W[k] = (y < 511) ? *(const float4*)(d + base + 512 + 4 * k) : z4;
            P[k] = *(const float4*)(p + base + 4 * k);
        }
        float uu[18], mm[18], ww[18], pv[16];
#pragma unroll
        for (int k = 0; k < 4; ++k) {
            mm[1+4*k]=M[k].x; mm[2+4*k]=M[k].y; mm[3+4*k]=M[k].z; mm[4+4*k]=M[k].w;
            uu[1+4*k]=U[k].x; uu[2+4*k]=U[k].y; uu[3+4*k]=U[k].z; uu[4+4*k]=U[k].w;
            ww[1+4*k]=W[k].x; ww[2+4*k]=W[k].y; ww[3+4*k]=W[k].z; ww[4+4*k]=W[k].w;
            pv[4*k]=P[k].x; pv[1+4*k]=P[k].y; pv[2+4*k]=P[k].z; pv[3+4*k]=P[k].w;
        }
        { float t;
          t = __shfl(mm[16], lane - 1); mm[0]  = (xl > 0)  ? t : 0.f;
          t = __shfl(mm[1],  lane + 1); mm[17] = (xl < 31) ? t : 0.f;
          t = __shfl(uu[16], lane - 1); uu[0]  = (xl > 0)  ? t : 0.f;
          t = __shfl(uu[1],  lane + 1); uu[17] = (xl < 31) ? t : 0.f;
          t = __shfl(ww[16], lane - 1); ww[0]  = (xl > 0)  ? t : 0.f;
          t = __shfl(ww[1],  lane + 1); ww[17] = (xl < 31) ? t : 0.f; }

        float gmn = 3.4e38f, gmx = -3.4e38f, dmn = 3.4e38f, dmx = -3.4e38f;
        float mf[NMOM];
#pragma unroll
        for (int m = 0; m < NMOM; ++m) mf[m] = 0.f;
        int fg = 0;
#pragma unroll
        for (int j = 1; j <= 16; ++j) {
            const float gx = (uu[j+1] - uu[j-1]) + 2.f * (mm[j+1] - mm[j-1]) + (ww[j+1] - ww[j-1]);
            const float gy = (ww[j-1] - uu[j-1]) + 2.f * (ww[j] - uu[j]) + (ww[j+1] - uu[j+1]);
            const float gm = sqrtf(gx * gx + gy * gy + 1e-8f);
            const float lap = uu[j] + mm[j-1] + mm[j+1] + ww[j] - 4.f * mm[j];
            const float e2x = __expf(0.2f * lap);            // tanh(z)=1-2/(e^{2z}+1)
            const float cv = 1.f - 2.f / (e2x + 1.f);
            const float pj = pv[j-1], dj = mm[j];
            gmn = fminf(gmn, gm); gmx = fmaxf(gmx, gm);
            dmn = fminf(dmn, dj); dmx = fmaxf(dmx, dj);
            fg += (pj > 0.5f) ? 1 : 0;
            const float et = pj - cv;
            mf[0] += pj;  mf[1] += pj * pj;
            mf[2] += gm;  mf[3] += gm * gm;  mf[4] += pj * gm;
            mf[5] += dj;  mf[6] += dj * dj;  mf[7] += pj * dj;
            mf[8] += et * et;
        }

        for (int o = 32; o > 0; o >>= 1) {
            gmn = fminf(gmn, __shfl_down(gmn, o));
            gmx = fmaxf(gmx, __shfl_down(gmx, o));
            dmn = fminf(dmn, __shfl_down(dmn, o));
            dmx = fmaxf(dmx, __shfl_down(dmx, o));
#pragma unroll
            for (int m = 0; m < NMOM; ++m) mf[m] += __shfl_down(mf[m], o);
            fg += __shfl_down(fg, o);
        }
        double (*sa)[NMOM] = (double(*)[NMOM])smem_d;     // 2x9 doubles
        float* sg0 = (float*)(smem_d + 18);
        float* sg1 = sg0 + 2; float* sd0 = sg0 + 4; float* sd1 = sg0 + 6;
        int* sf = (int*)(sg0 + 8);
        if (lane == 0) {
            sg0[wid] = gmn; sg1[wid] = gmx; sd0[wid] = dmn; sd1[wid] = dmx; sf[wid] = fg;
#pragma unroll
            for (int m = 0; m < NMOM; ++m) sa[wid][m] = (double)mf[m];
        }
        __syncthreads();
        if (tid == 0) {
            double mo[NMOM];
#pragma unroll
            for (int m = 0; m < NMOM; ++m) mo[m] = sa[0][m] + sa[1][m];
            gmn = fminf(gmn, sg0[1]); gmx = fmaxf(gmx, sg1[1]);
            dmn = fminf(dmn, sd0[1]); dmx = fmaxf(dmx, sd1[1]);
            fg += sf[1];
            const int bid = b * 128 + fb;
            pmm[bid] = make_float4(gmn, gmx, dmn, dmx);
#pragma unroll
            for (int m = 0; m < NMOM; ++m) pblk[(size_t)bid * NMOM + m] = mo[m];
            pfg[bid] = fg;
        }
        return;
    }

    // ================= local CCL role =================
    if (blockIdx.y >= nloc) return;
    const int slot = blockIdx.y;
    const float* p = pred + (size_t)(b0 + slot) * IMG_HW;
    int* L = Lp + (size_t)slot * NODES_PER_IMG;
    int* C = Cp + (size_t)slot * NODES_PER_IMG;
    const int pair = blockIdx.x * 2 + wid;      // 0..127
    const int tile0 = pair * 2;
    const int half = lane >> 5;
    const int tile = tile0 + half;
    const int tx0 = (tile0 & 15) * 32;          // 64-wide strip origin
    const int ty  = (tile0 >> 4) * 32;
    const int r = lane & 31;

    int* lab  = smem;            // 2x1024
    int* lcnt = smem + 2048;     // 2x1024
    int* ns   = smem + 4096;     // 2x2
    int* labw = lab + wid * 1024;
    int* lcw  = lcnt + wid * 1024;
    int* nsw  = ns + wid * 2;
    if (lane < 2) nsw[lane] = 0;
    const int nbase = half * 512;

    // Phase A: 8 float4 loads + 4 ballots each; reassemble my row mask.
    const int myit = r >> 2;
    unsigned long long q0 = 0, q1 = 0, q2 = 0, q3 = 0;
    for (int it = 0; it < 8; ++it) {
        const int row = it * 4 + (lane >> 4);
        const float4 v = *(const float4*)(p + (ty + row) * IMG_W + tx0 + (lane & 15) * 4);
        const unsigned long long t0 = __ballot(v.x > 0.5f);
        const unsigned long long t1 = __ballot(v.y > 0.5f);
        const unsigned long long t2 = __ballot(v.z > 0.5f);
        const unsigned long long t3 = __ballot(v.w > 0.5f);
        if (it == myit) { q0 = t0; q1 = t1; q2 = t2; q3 = t3; }
    }
#pragma unroll
    for (int k = 0; k < 16; ++k) {
        const int n = k * 64 + lane;
        labw[n] = n; lcw[n] = 0;
    }
    const int sh = 16 * (r & 3) + 8 * half;
    const unsigned m = spread4((unsigned)(q0 >> sh))
                     | (spread4((unsigned)(q1 >> sh)) << 1)
                     | (spread4((unsigned)(q2 >> sh)) << 2)
                     | (spread4((unsigned)(q3 >> sh)) << 3);
    const int mpl = __shfl((int)m, lane - 1);
    const unsigned mp = (r >= 1) ? (unsigned)mpl : 0u;

    const unsigned sm  = m  & ~(m << 1);
    const unsigned smp = mp & ~(mp << 1);

    // Phase B: vertical merges between overlapping runs of rows r-1, r.
    if (r >= 1) {
        unsigned ov = m & mp;
        while (ov) {
            const int bpos = __builtin_ctz(ov);
            const int sa2 = run_start(m, bpos);
            const int ea = sa2 + run_len(m, sa2) - 1;
            const int sb = run_start(mp, bpos);
            const int eb = sb + run_len(mp, sb) - 1;
            uf_merge(labw, nbase + run_idx(sm, sa2) * 32 + r,
                            nbase + run_idx(smp, sb) * 32 + (r - 1));
            const int e = (ea < eb) ? ea : eb;
            ov = (e >= 31) ? 0u : (ov & ~((1u << (e + 1)) - 1u));
        }
    }

    // Phase C: per-run sizes + boundary TOUCH + path compression.
    {
        unsigned rs = sm; int j = 0;
        while (rs) {
            const int st = __builtin_ctz(rs); rs &= rs - 1;
            const int len = run_len(m, st);
            const int e = st + len - 1;
            const int node = nbase + j * 32 + r; ++j;
            const int root = uf_findv(labw, node);
            if (root != node) labw[node] = root;
            atomicAdd(&lcw[root], len);
            if (r == 0 || r == 31 || st == 0 || e == 31)
                atomicOr(&lcw[root], TOUCH);
        }
    }

    // Phase D: interior roots -> locmax; boundary roots -> emit packed node.
    int locmax = 0;
    {
        unsigned rs = sm; int j = 0;
        while (rs) {
            rs &= rs - 1;
            const int node = nbase + j * 32 + r; ++j;
            if (labw[node] != node) continue;
            const int c = lcw[node];
            if (c & TOUCH) {
                const int sl = atomicAdd(&nsw[half], 1);
                const int gn = tile * NODES_PER_TILE + 128 + sl;
                L[gn] = gn;
                C[gn] = c & ~TOUCH;
                lcw[node] = gn;       // root -> packed id map
            } else {
                locmax = max(locmax, c);
            }
        }
    }
    for (int o = 32; o > 0; o >>= 1) locmax = max(locmax, __shfl_down(locmax, o));

    // Ring phase: 124 entries per tile x 2 tiles.
#pragma unroll
    for (int t = 0; t < 4; ++t) {
        const int i = lane + t * 64;           // 0..255
        const int h = i >> 7, idx = i & 127;
        const int tb = (tile0 + h) * NODES_PER_TILE;
        if (idx < 124) {
            int x, yy;
            ring_decode(idx, x, yy);
            const unsigned my = (unsigned)__shfl((int)m, h * 32 + yy);
            int val = -1;
            if ((my >> x) & 1u) {
                const unsigned smy = my & ~(my << 1);
                const int node = h * 512 + run_idx(smy, x) * 32 + yy;
                const int root = uf_findv(labw, node);
                val = lcw[root];
            }
            L[tb + idx] = val;
        } else {
            L[tb + idx] = -1;
        }
    }

    if (lane == 0) pairmax[slot * PAIRS + pair] = locmax;   // plain store
    if (lane < 2) nslot[slot * TILES + tile0 + lane] = nsw[lane];
}

// Fused: blockIdx.x < 60 -> seam merges for image blockIdx.y; blockIdx.x
// 60..85 (y==0, featOn chunk only) -> stage-2 reduce (also maxcnt=0 init,
// before any k_tail). block 256.
__global__ void k_mid(int* __restrict__ Lp,
                      const float4* __restrict__ pmm, const double* __restrict__ pblk,
                      const int* __restrict__ pfg, Scal* s) {
    const int wid = threadIdx.x >> 6, lane = threadIdx.x & 63;
    if (blockIdx.x < 60) {
        const int slot = blockIdx.y;
        int* L = Lp + (size_t)slot * NODES_PER_IMG;
        const int e = blockIdx.x * 256 + threadIdx.x;
        int a, b;
        if (e < 7680) {             // vertical seam sc (0..14), y (0..511)
            const int sc = e / 512, y = e - sc * 512;
            const int ly = y & 31;
            const int tL = (y >> 5) * 16 + sc;
            const int iL = (ly == 0) ? 31 : (ly == 31) ? 63 : (93 + ly);
            const int iR = (ly == 0) ? 0  : (ly == 31) ? 32 : (63 + ly);
            a = tL * NODES_PER_TILE + iL;
            b = (tL + 1) * NODES_PER_TILE + iR;
        } else {                    // horizontal seam sr (0..14), x (0..511)
            const int e2 = e - 7680;
            const int sr = e2 / 512, x = e2 - sr * 512;
            const int lx = x & 31;
            const int tT = sr * 16 + (x >> 5);
            a = tT * NODES_PER_TILE + 32 + lx;
            b = (tT + 16) * NODES_PER_TILE + lx;
        }
        if (L[a] >= 0 && L[b] >= 0) uf_merge(L, a, b);
        return;
    }
    if (blockIdx.y != 0) return;
    const int rb = blockIdx.x - 60;     // 0..25
    if (rb < IMG_B) {
        const int b = rb;
        double ar = 0.0; int fg = 0;
        if (threadIdx.x < 128) {
            const int k = b * 128 + threadIdx.x;
            ar = pblk[(size_t)k * NMOM + 0];
            fg = pfg[k];
        }
        for (int o = 32; o > 0; o >>= 1) { ar += __shfl_down(ar, o); fg += __shfl_down(fg, o); }
        __shared__ double sa[4];
        __shared__ int sf[4];
        if (lane == 0) { sa[wid] = ar; sf[wid] = fg; }
        __syncthreads();
        if (threadIdx.x == 0) {
            ar += sa[1]; fg += sf[1];
            s->area[b] = ar; s->fgcnt[b] = fg;
            s->maxcnt[b] = 0;
        }
    } else if (rb == IMG_B) {
        float gmn = 3.4e38f, gmx = -3.4e38f, dmn = 3.4e38f, dmx = -3.4e38f;
        for (int k = threadIdx.x; k < NPART; k += 256) {
            const float4 v = pmm[k];
            gmn = fminf(gmn, v.x); gmx = fmaxf(gmx, v.y);
            dmn = fminf(dmn, v.z); dmx = fmaxf(dmx, v.w);
        }
        for (int o = 32; o > 0; o >>= 1) {
            gmn = fminf(gmn, __shfl_down(gmn, o));
            gmx = fmaxf(gmx, __shfl_down(gmx, o));
            dmn = fminf(dmn, __shfl_down(dmn, o));
            dmx = fmaxf(dmx, __shfl_down(dmx, o));
        }
        __shared__ float sg0[4], sg1[4], sd0[4], sd1[4];
        if (lane == 0) { sg0[wid] = gmn; sg1[wid] = gmx; sd0[wid] = dmn; sd1[wid] = dmx; }
        __syncthreads();
        if (threadIdx.x == 0) {
            for (int w = 1; w < 4; ++w) {
                gmn = fminf(gmn, sg0[w]); gmx = fmaxf(gmx, sg1[w]);
                dmn = fminf(dmn, sd0[w]); dmx = fmaxf(dmx, sd1[w]);
            }
            s->gmin = gmn; s->gmax = gmx; s->dmin = dmn; s->dmax = dmx;
        }
    } else {
        const int m = rb - IMG_B - 1;   // 0..NMOM-1
        double acc = 0.0;
        for (int k = threadIdx.x; k < NPART; k += 256) acc += pblk[(size_t)k * NMOM + m];
        for (int o = 32; o > 0; o >>= 1) acc += __shfl_down(acc, o);
        __shared__ double sa[4];
        if (lane == 0) sa[wid] = acc;
        __syncthreads();
        if (threadIdx.x == 0) {
            for (int w = 1; w < 4; ++w) acc += sa[w];
            s->mom[m] = acc;
        }
    }
}

// Fused flush+max: last-adder-reports-total. grid (65, nimg), block 256.
__global__ void k_tail(const int* __restrict__ Lp, int* __restrict__ Cp,
                       const int* __restrict__ nslot, const int* __restrict__ pairmax,
                       Scal* s, int b0) {
    const int img = blockIdx.y;
    int m = 0;
    if (blockIdx.x < 64) {
        const int* L = Lp + (size_t)img * NODES_PER_IMG;
        int* C = Cp + (size_t)img * NODES_PER_IMG;
        const int sidx = blockIdx.x * 256 + threadIdx.x;
        const int tile = sidx >> 6, sl = sidx & 63;
        if (sl < nslot[img * TILES + tile]) {
            const int g = tile * NODES_PER_TILE + 128 + sl;
            const int sz = C[g];
            const int rt = uf_findv(L, g);
            if (rt != g) m = atomicAdd(&C[rt], sz) + sz;
            else         m = sz;
        }
    } else {
        if (threadIdx.x < PAIRS) m = pairmax[img * PAIRS + threadIdx.x];
    }
    for (int o = 32; o > 0; o >>= 1) m = max(m, __shfl_down(m, o));
    __shared__ int sm[4];
    const int wid = threadIdx.x >> 6, lane = threadIdx.x & 63;
    if (lane == 0) sm[wid] = m;
    __syncthreads();
    if (threadIdx.x == 0) {
        for (int w = 1; w < 4; ++w) m = max(m, sm[w]);
        if (m > 0) atomicMax(&s->maxcnt[b0 + img], m);
    }
}

// Final: closed-form similarity from moments + conn + scale. 1 thread.
__global__ void k_final(const Scal* __restrict__ s, float* __restrict__ out) {
    const double N = (double)IMG_B * (double)IMG_HW;
    const float gdenf = s->gmax - s->gmin + 1e-8f;
    const float ddenf = s->dmax - s->dmin + 1e-8f;
    const double a = 1.0 / (double)gdenf, bb = 1.0 / (double)ddenf;
    const double gmin = (double)s->gmin, dmin = (double)s->dmin;
    const double S_p = s->mom[0], S_pp = s->mom[1];
    const double S_g = s->mom[2], S_gg = s->mom[3], S_pg = s->mom[4];
    const double S_d = s->mom[5], S_dd = s->mom[6], S_pd = s->mom[7];
    const double S_t = s->mom[8];
    const double sum_g = S_pp - 2.0 * a * (S_pg - gmin * S_p)
                       + a * a * (S_gg - 2.0 * gmin * S_g + gmin * gmin * N);
    const double sum_d = S_pp - 2.0 * bb * (S_pd - dmin * S_p)
                       + bb * bb * (S_dd - 2.0 * dmin * S_d + dmin * dmin * N);
    const double sim = (sum_g + sum_d + S_t) / (3.0 * N);

    const double tp = (double)IMG_HW;
    const double tmin = 0.1 * tp, tmax = 0.3 * tp;
    double conn = 0.0, scale = 0.0;
    for (int b = 0; b < IMG_B; ++b) {
        const int total = s->fgcnt[b];
        if (total > 0) conn += 1.0 - (double)s->maxcnt[b] / (double)total;
        const double ar = s->area[b];
        scale += fmax(ar - tmax, 0.0) + fmax(tmin - ar, 0.0);
    }
    conn /= (double)IMG_B;
    scale = (scale / (double)IMG_B) / tp;
    const double total = sim + 0.1 * conn + 0.05 * scale;
    out[0] = (float)(0.1 * total);
}

extern "C" void kernel_launch(void* const* d_in, const int* in_sizes, int n_in,
                              void* d_out, int out_size, void* d_ws, size_t ws_size,
                              hipStream_t stream) {
    const float* pred = (const float*)d_in[0];  // [16,1,512,512]
    const float* dem  = (const float*)d_in[1];  // [16,1,512,512]
    float* out = (float*)d_out;

    char* ws = (char*)d_ws;
    Scal* s = (Scal*)ws;
    float4* pmm  = (float4*)(ws + OFF_PMM);
    double* pblk = (double*)(ws + OFF_MOM);
    int*    pfg  = (int*)(ws + OFF_FG);
    int* scratch = (int*)(ws + OFF_SCR);
    const size_t avail_ints = (ws_size > OFF_SCR) ? (ws_size - OFF_SCR) / 4 : 0;
    const size_t per_img = 2ull * NODES_PER_IMG + TILES + PAIRS;

    long long chunk = (long long)(avail_ints / per_img);
    if (chunk < 1) chunk = 1;
    if (chunk > IMG_B) chunk = IMG_B;

    for (int b0 = 0; b0 < IMG_B; b0 += (int)chunk) {
        const int n = (int)((b0 + chunk <= IMG_B) ? chunk : (IMG_B - b0));
        int* Lp      = scratch;
        int* Cp      = scratch + (size_t)chunk * NODES_PER_IMG;
        int* nslotp  = scratch + 2ull * chunk * NODES_PER_IMG;
        int* pairmax = nslotp + (size_t)chunk * TILES;
        const int featOn = (b0 == 0) ? 1 : 0;
        const int gx = featOn ? 192 : 64;
        const int gy = featOn ? IMG_B : n;
        hipLaunchKernelGGL(k_main, dim3(gx, gy), dim3(128), 0, stream,
                           dem, pred, pmm, pblk, pfg, Lp, Cp, nslotp, pairmax,
                           b0, n, featOn);
        hipLaunchKernelGGL(k_mid, dim3(featOn ? 86 : 60, n), dim3(256), 0, stream,
                           Lp, pmm, pblk, pfg, s);
        hipLaunchKernelGGL(k_tail, dim3(65, n), dim3(256), 0, stream,
                           Lp, Cp, nslotp, pairmax, s, b0);
    }

    hipLaunchKernelGGL(k_final, dim3(1), dim3(1), 0, stream, s, out);
}

// Round 15
// 62.448 us; speedup vs baseline: 2.4114x; 1.0796x over previous
//
#include <hip/hip_runtime.h>
#include <math.h>

#define IMG_B 16
#define IMG_H 512
#define IMG_W 512
#define IMG_HW (IMG_H * IMG_W)
#define NPART 4096            // 256 feat blocks/image * 16 images

// moment indices: 0:S_p 1:S_pp 2:S_g 3:S_gg 4:S_pg 5:S_d 6:S_dd 7:S_pd 8:S_t
#define NMOM 9

// 32x32 tile CCL, packed boundary graph: per tile 192 nodes
#define TILES 256             // per image (16x16)
#define NODES_PER_TILE 192
#define NODES_PER_IMG (TILES * NODES_PER_TILE)   // 49152
#define PAIRS 128             // tile pairs per image
#define TOUCH (1 << 30)

struct Scal {
    float gmin, gmax, dmin, dmax;
    double mom[NMOM];
    double area[IMG_B];
    int fgcnt[IMG_B];
    int maxcnt[IMG_B];
};

// ws layout (bytes):
//   0       Scal (padded to 512)
//   512     float4 pmm[NPART]            (65536)
//   66048   double pblk[NPART][NMOM]     (294912)
//   360960  int    pfg[NPART]            (16384)
//   377344  scratch: packed labels / counts / nslot / pairmax
#define OFF_PMM   512
#define OFF_MOM   66048
#define OFF_FG    360960
#define OFF_SCR   377344

// ---- union-find (LDS or global) ----
__device__ __forceinline__ int uf_findv(const int* L, int p) {
    while (true) { const int q = ((volatile const int*)L)[p]; if (q == p) return p; p = q; }
}
__device__ __forceinline__ void uf_merge(int* L, int a, int b) {
    while (true) {
        a = uf_findv(L, a);
        b = uf_findv(L, b);
        if (a == b) return;
        if (a < b) { int t = a; a = b; b = t; }
        const int old = atomicMin(&L[a], b);
        if (old == a) return;
        a = old;
    }
}

// ---- run bit helpers ----
__device__ __forceinline__ int run_start(unsigned m, int b) {
    const unsigned below = ~m & ((b == 0) ? 0u : ((1u << b) - 1u));
    return below ? (int)(32u - (unsigned)__builtin_clz(below)) : 0;
}
__device__ __forceinline__ int run_len(unsigned m, int s) {
    const unsigned inv = ~(m >> s);
    return inv ? __builtin_ctz(inv) : (32 - s);
}
__device__ __forceinline__ int run_idx(unsigned sm, int c) {
    return __popc(sm & (unsigned)((2ull << c) - 1ull)) - 1;
}
// spread 8 bits to stride-4 positions (bit i -> bit 4i)
__device__ __forceinline__ unsigned spread4(unsigned x) {
    x &= 0xFFu;
    x = (x | (x << 12)) & 0x000F000Fu;
    x = (x | (x << 6))  & 0x03030303u;
    x = (x | (x << 3))  & 0x11111111u;
    return x;
}

// ring index map (124 ring px in 128 slots)
__device__ __forceinline__ void ring_decode(int i, int& x, int& y) {
    if (i < 32)      { x = i;      y = 0;      }
    else if (i < 64) { x = i - 32; y = 31;     }
    else if (i < 94) { x = 0;      y = i - 63; }
    else             { x = 31;     y = i - 93; }
}

// Fused pass, BLOCK = 128 (2 waves). blockIdx.x < 64 -> local CCL role
// (2 pairs/block); >= 64 -> feat role (8 px/thread, wave == one full row,
// 256 blocks/image).
__global__ void k_main(const float* __restrict__ dem, const float* __restrict__ pred,
                       float4* __restrict__ pmm, double* __restrict__ pblk,
                       int* __restrict__ pfg,
                       int* __restrict__ Lp, int* __restrict__ Cp,
                       int* __restrict__ nslot, int* __restrict__ pairmax,
                       int b0, int nloc, int featOn) {
    __shared__ double smem_d[2052];   // 16416 B
    int* smem = (int*)smem_d;
    const int tid = threadIdx.x;
    const int lane = tid & 63, wid = tid >> 6;   // wid in {0,1}

    if (blockIdx.x >= 64) {
        // ================= feat role: 8 px/thread =================
        if (!featOn) return;
        const int fb = blockIdx.x - 64;        // 0..255
        const int b = blockIdx.y;              // image
        const size_t off = (size_t)b * IMG_HW;
        const float* d = dem + off;
        const float* p = pred + off;
        const int base = fb * 1024 + tid * 8;  // wave == one full row
        const int y = base >> 9;

        const float4 z4 = make_float4(0.f, 0.f, 0.f, 0.f);
        float4 m0 = *(const float4*)(d + base);
        float4 m1 = *(const float4*)(d + base + 4);
        float4 u0 = z4, u1 = z4, w0 = z4, w1 = z4;
        if (y > 0)   { u0 = *(const float4*)(d + base - 512); u1 = *(const float4*)(d + base - 508); }
        if (y < 511) { w0 = *(const float4*)(d + base + 512); w1 = *(const float4*)(d + base + 516); }

        float uu[10], mm[10], ww[10];
        { float t;
          t = __shfl(m1.w, lane - 1); mm[0] = (lane > 0)  ? t : 0.f;
          t = __shfl(m0.x, lane + 1); mm[9] = (lane < 63) ? t : 0.f;
          t = __shfl(u1.w, lane - 1); uu[0] = (lane > 0)  ? t : 0.f;
          t = __shfl(u0.x, lane + 1); uu[9] = (lane < 63) ? t : 0.f;
          t = __shfl(w1.w, lane - 1); ww[0] = (lane > 0)  ? t : 0.f;
          t = __shfl(w0.x, lane + 1); ww[9] = (lane < 63) ? t : 0.f; }
        uu[1]=u0.x; uu[2]=u0.y; uu[3]=u0.z; uu[4]=u0.w; uu[5]=u1.x; uu[6]=u1.y; uu[7]=u1.z; uu[8]=u1.w;
        mm[1]=m0.x; mm[2]=m0.y; mm[3]=m0.z; mm[4]=m0.w; mm[5]=m1.x; mm[6]=m1.y; mm[7]=m1.z; mm[8]=m1.w;
        ww[1]=w0.x; ww[2]=w0.y; ww[3]=w0.z; ww[4]=w0.w; ww[5]=w1.x; ww[6]=w1.y; ww[7]=w1.z; ww[8]=w1.w;

        const float4 p0 = *(const float4*)(p + base);
        const float4 p1 = *(const float4*)(p + base + 4);
        const float pv[8] = {p0.x, p0.y, p0.z, p0.w, p1.x, p1.y, p1.z, p1.w};

        float gmn = 3.4e38f, gmx = -3.4e38f, dmn = 3.4e38f, dmx = -3.4e38f;
        float mf[NMOM];
#pragma unroll
        for (int m = 0; m < NMOM; ++m) mf[m] = 0.f;
        int fg = 0;
#pragma unroll
        for (int j = 0; j < 8; ++j) {
            const float gx = (uu[j+2] - uu[j]) + 2.f * (mm[j+2] - mm[j]) + (ww[j+2] - ww[j]);
            const float gy = (ww[j] - uu[j]) + 2.f * (ww[j+1] - uu[j+1]) + (ww[j+2] - uu[j+2]);
            const float gm = sqrtf(gx * gx + gy * gy + 1e-8f);
            const float lap = uu[j+1] + mm[j] + mm[j+2] + ww[j+1] - 4.f * mm[j+1];
            const float e2x = __expf(0.2f * lap);            // tanh(z)=1-2/(e^{2z}+1)
            const float cv = 1.f - 2.f / (e2x + 1.f);
            const float pj = pv[j], dj = mm[j+1];
            gmn = fminf(gmn, gm); gmx = fmaxf(gmx, gm);
            dmn = fminf(dmn, dj); dmx = fmaxf(dmx, dj);
            fg += (pj > 0.5f) ? 1 : 0;
            const float et = pj - cv;
            mf[0] += pj;  mf[1] += pj * pj;
            mf[2] += gm;  mf[3] += gm * gm;  mf[4] += pj * gm;
            mf[5] += dj;  mf[6] += dj * dj;  mf[7] += pj * dj;
            mf[8] += et * et;
        }

        for (int o = 32; o > 0; o >>= 1) {
            gmn = fminf(gmn, __shfl_down(gmn, o));
            gmx = fmaxf(gmx, __shfl_down(gmx, o));
            dmn = fminf(dmn, __shfl_down(dmn, o));
            dmx = fmaxf(dmx, __shfl_down(dmx, o));
#pragma unroll
            for (int m = 0; m < NMOM; ++m) mf[m] += __shfl_down(mf[m], o);
            fg += __shfl_down(fg, o);
        }
        double (*sa)[NMOM] = (double(*)[NMOM])smem_d;     // 2x9 doubles
        float* sg0 = (float*)(smem_d + 18);
        float* sg1 = sg0 + 2; float* sd0 = sg0 + 4; float* sd1 = sg0 + 6;
        int* sf = (int*)(sg0 + 8);
        if (lane == 0) {
            sg0[wid] = gmn; sg1[wid] = gmx; sd0[wid] = dmn; sd1[wid] = dmx; sf[wid] = fg;
#pragma unroll
            for (int m = 0; m < NMOM; ++m) sa[wid][m] = (double)mf[m];
        }
        __syncthreads();
        if (tid == 0) {
            double mo[NMOM];
#pragma unroll
            for (int m = 0; m < NMOM; ++m) mo[m] = sa[0][m] + sa[1][m];
            gmn = fminf(gmn, sg0[1]); gmx = fmaxf(gmx, sg1[1]);
            dmn = fminf(dmn, sd0[1]); dmx = fmaxf(dmx, sd1[1]);
            fg += sf[1];
            const int bid = b * 256 + fb;
            pmm[bid] = make_float4(gmn, gmx, dmn, dmx);
#pragma unroll
            for (int m = 0; m < NMOM; ++m) pblk[(size_t)bid * NMOM + m] = mo[m];
            pfg[bid] = fg;
        }
        return;
    }

    // ================= local CCL role =================
    if (blockIdx.y >= nloc) return;
    const int slot = blockIdx.y;
    const float* p = pred + (size_t)(b0 + slot) * IMG_HW;
    int* L = Lp + (size_t)slot * NODES_PER_IMG;
    int* C = Cp + (size_t)slot * NODES_PER_IMG;
    const int pair = blockIdx.x * 2 + wid;      // 0..127
    const int tile0 = pair * 2;
    const int half = lane >> 5;
    const int tile = tile0 + half;
    const int tx0 = (tile0 & 15) * 32;          // 64-wide strip origin
    const int ty  = (tile0 >> 4) * 32;
    const int r = lane & 31;

    int* lab  = smem;            // 2x1024
    int* lcnt = smem + 2048;     // 2x1024
    int* ns   = smem + 4096;     // 2x2
    int* labw = lab + wid * 1024;
    int* lcw  = lcnt + wid * 1024;
    int* nsw  = ns + wid * 2;
    if (lane < 2) nsw[lane] = 0;
    const int nbase = half * 512;

    // Phase A: 8 float4 loads + 4 ballots each; reassemble my row mask.
    const int myit = r >> 2;
    unsigned long long q0 = 0, q1 = 0, q2 = 0, q3 = 0;
    for (int it = 0; it < 8; ++it) {
        const int row = it * 4 + (lane >> 4);
        const float4 v = *(const float4*)(p + (ty + row) * IMG_W + tx0 + (lane & 15) * 4);
        const unsigned long long t0 = __ballot(v.x > 0.5f);
        const unsigned long long t1 = __ballot(v.y > 0.5f);
        const unsigned long long t2 = __ballot(v.z > 0.5f);
        const unsigned long long t3 = __ballot(v.w > 0.5f);
        if (it == myit) { q0 = t0; q1 = t1; q2 = t2; q3 = t3; }
    }
#pragma unroll
    for (int k = 0; k < 16; ++k) {
        const int n = k * 64 + lane;
        labw[n] = n; lcw[n] = 0;
    }
    const int sh = 16 * (r & 3) + 8 * half;
    const unsigned m = spread4((unsigned)(q0 >> sh))
                     | (spread4((unsigned)(q1 >> sh)) << 1)
                     | (spread4((unsigned)(q2 >> sh)) << 2)
                     | (spread4((unsigned)(q3 >> sh)) << 3);
    const int mpl = __shfl((int)m, lane - 1);
    const unsigned mp = (r >= 1) ? (unsigned)mpl : 0u;

    const unsigned sm  = m  & ~(m << 1);
    const unsigned smp = mp & ~(mp << 1);

    // Phase B: vertical merges between overlapping runs of rows r-1, r.
    if (r >= 1) {
        unsigned ov = m & mp;
        while (ov) {
            const int bpos = __builtin_ctz(ov);
            const int sa2 = run_start(m, bpos);
            const int ea = sa2 + run_len(m, sa2) - 1;
            const int sb = run_start(mp, bpos);
            const int eb = sb + run_len(mp, sb) - 1;
            uf_merge(labw, nbase + run_idx(sm, sa2) * 32 + r,
                            nbase + run_idx(smp, sb) * 32 + (r - 1));
            const int e = (ea < eb) ? ea : eb;
            ov = (e >= 31) ? 0u : (ov & ~((1u << (e + 1)) - 1u));
        }
    }

    // Phase C: per-run sizes + boundary TOUCH + path compression.
    {
        unsigned rs = sm; int j = 0;
        while (rs) {
            const int st = __builtin_ctz(rs); rs &= rs - 1;
            const int len = run_len(m, st);
            const int e = st + len - 1;
            const int node = nbase + j * 32 + r; ++j;
            const int root = uf_findv(labw, node);
            if (root != node) labw[node] = root;
            atomicAdd(&lcw[root], len);
            if (r == 0 || r == 31 || st == 0 || e == 31)
                atomicOr(&lcw[root], TOUCH);
        }
    }

    // Phase D: interior roots -> locmax; boundary roots -> emit packed node.
    int locmax = 0;
    {
        unsigned rs = sm; int j = 0;
        while (rs) {
            rs &= rs - 1;
            const int node = nbase + j * 32 + r; ++j;
            if (labw[node] != node) continue;
            const int c = lcw[node];
            if (c & TOUCH) {
                const int sl = atomicAdd(&nsw[half], 1);
                const int gn = tile * NODES_PER_TILE + 128 + sl;
                L[gn] = gn;
                C[gn] = c & ~TOUCH;
                lcw[node] = gn;       // root -> packed id map
            } else {
                locmax = max(locmax, c);
            }
        }
    }
    for (int o = 32; o > 0; o >>= 1) locmax = max(locmax, __shfl_down(locmax, o));

    // Ring phase: 124 entries per tile x 2 tiles.
#pragma unroll
    for (int t = 0; t < 4; ++t) {
        const int i = lane + t * 64;           // 0..255
        const int h = i >> 7, idx = i & 127;
        const int tb = (tile0 + h) * NODES_PER_TILE;
        if (idx < 124) {
            int x, yy;
            ring_decode(idx, x, yy);
            const unsigned my = (unsigned)__shfl((int)m, h * 32 + yy);
            int val = -1;
            if ((my >> x) & 1u) {
                const unsigned smy = my & ~(my << 1);
                const int node = h * 512 + run_idx(smy, x) * 32 + yy;
                const int root = uf_findv(labw, node);
                val = lcw[root];
            }
            L[tb + idx] = val;
        } else {
            L[tb + idx] = -1;
        }
    }

    if (lane == 0) pairmax[slot * PAIRS + pair] = locmax;   // plain store
    if (lane < 2) nslot[slot * TILES + tile0 + lane] = nsw[lane];
}

// Fused: blockIdx.x < 60 -> seam merges for image blockIdx.y; blockIdx.x
// 60..85 (y==0, featOn chunk only) -> stage-2 reduce (also maxcnt=0 init,
// before any k_tail). block 256.
__global__ void k_mid(int* __restrict__ Lp,
                      const float4* __restrict__ pmm, const double* __restrict__ pblk,
                      const int* __restrict__ pfg, Scal* s) {
    const int wid = threadIdx.x >> 6, lane = threadIdx.x & 63;
    if (blockIdx.x < 60) {
        const int slot = blockIdx.y;
        int* L = Lp + (size_t)slot * NODES_PER_IMG;
        const int e = blockIdx.x * 256 + threadIdx.x;
        int a, b;
        if (e < 7680) {             // vertical seam sc (0..14), y (0..511)
            const int sc = e / 512, y = e - sc * 512;
            const int ly = y & 31;
            const int tL = (y >> 5) * 16 + sc;
            const int iL = (ly == 0) ? 31 : (ly == 31) ? 63 : (93 + ly);
            const int iR = (ly == 0) ? 0  : (ly == 31) ? 32 : (63 + ly);
            a = tL * NODES_PER_TILE + iL;
            b = (tL + 1) * NODES_PER_TILE + iR;
        } else {                    // horizontal seam sr (0..14), x (0..511)
            const int e2 = e - 7680;
            const int sr = e2 / 512, x = e2 - sr * 512;
            const int lx = x & 31;
            const int tT = sr * 16 + (x >> 5);
            a = tT * NODES_PER_TILE + 32 + lx;
            b = (tT + 16) * NODES_PER_TILE + lx;
        }
        if (L[a] >= 0 && L[b] >= 0) uf_merge(L, a, b);
        return;
    }
    if (blockIdx.y != 0) return;
    const int rb = blockIdx.x - 60;     // 0..25
    if (rb < IMG_B) {
        const int b = rb;
        const int k = b * 256 + threadIdx.x;      // 256 partials per image
        double ar = pblk[(size_t)k * NMOM + 0];
        int fg = pfg[k];
        for (int o = 32; o > 0; o >>= 1) { ar += __shfl_down(ar, o); fg += __shfl_down(fg, o); }
        __shared__ double sa[4];
        __shared__ int sf[4];
        if (lane == 0) { sa[wid] = ar; sf[wid] = fg; }
        __syncthreads();
        if (threadIdx.x == 0) {
            for (int w = 1; w < 4; ++w) { ar += sa[w]; fg += sf[w]; }
            s->area[b] = ar; s->fgcnt[b] = fg;
            s->maxcnt[b] = 0;
        }
    } else if (rb == IMG_B) {
        float gmn = 3.4e38f, gmx = -3.4e38f, dmn = 3.4e38f, dmx = -3.4e38f;
        for (int k = threadIdx.x; k < NPART; k += 256) {
            const float4 v = pmm[k];
            gmn = fminf(gmn, v.x); gmx = fmaxf(gmx, v.y);
            dmn = fminf(dmn, v.z); dmx = fmaxf(dmx, v.w);
        }
        for (int o = 32; o > 0; o >>= 1) {
            gmn = fminf(gmn, __shfl_down(gmn, o));
            gmx = fmaxf(gmx, __shfl_down(gmx, o));
            dmn = fminf(dmn, __shfl_down(dmn, o));
            dmx = fmaxf(dmx, __shfl_down(dmx, o));
        }
        __shared__ float sg0[4], sg1[4], sd0[4], sd1[4];
        if (lane == 0) { sg0[wid] = gmn; sg1[wid] = gmx; sd0[wid] = dmn; sd1[wid] = dmx; }
        __syncthreads();
        if (threadIdx.x == 0) {
            for (int w = 1; w < 4; ++w) {
                gmn = fminf(gmn, sg0[w]); gmx = fmaxf(gmx, sg1[w]);
                dmn = fminf(dmn, sd0[w]); dmx = fmaxf(dmx, sd1[w]);
            }
            s->gmin = gmn; s->gmax = gmx; s->dmin = dmn; s->dmax = dmx;
        }
    } else {
        const int m = rb - IMG_B - 1;   // 0..NMOM-1
        double acc = 0.0;
        for (int k = threadIdx.x; k < NPART; k += 256) acc += pblk[(size_t)k * NMOM + m];
        for (int o = 32; o > 0; o >>= 1) acc += __shfl_down(acc, o);
        __shared__ double sa[4];
        if (lane == 0) sa[wid] = acc;
        __syncthreads();
        if (threadIdx.x == 0) {
            for (int w = 1; w < 4; ++w) acc += sa[w];
            s->mom[m] = acc;
        }
    }
}

// Fused flush+max: last-adder-reports-total. grid (65, nimg), block 256.
__global__ void k_tail(const int* __restrict__ Lp, int* __restrict__ Cp,
                       const int* __restrict__ nslot, const int* __restrict__ pairmax,
                       Scal* s, int b0) {
    const int img = blockIdx.y;
    int m = 0;
    if (blockIdx.x < 64) {
        const int* L = Lp + (size_t)img * NODES_PER_IMG;
        int* C = Cp + (size_t)img * NODES_PER_IMG;
        const int sidx = blockIdx.x * 256 + threadIdx.x;
        const int tile = sidx >> 6, sl = sidx & 63;
        if (sl < nslot[img * TILES + tile]) {
            const int g = tile * NODES_PER_TILE + 128 + sl;
            const int sz = C[g];
            const int rt = uf_findv(L, g);
            if (rt != g) m = atomicAdd(&C[rt], sz) + sz;
            else         m = sz;
        }
    } else {
        if (threadIdx.x < PAIRS) m = pairmax[img * PAIRS + threadIdx.x];
    }
    for (int o = 32; o > 0; o >>= 1) m = max(m, __shfl_down(m, o));
    __shared__ int sm[4];
    const int wid = threadIdx.x >> 6, lane = threadIdx.x & 63;
    if (lane == 0) sm[wid] = m;
    __syncthreads();
    if (threadIdx.x == 0) {
        for (int w = 1; w < 4; ++w) m = max(m, sm[w]);
        if (m > 0) atomicMax(&s->maxcnt[b0 + img], m);
    }
}

// Final: closed-form similarity from moments + conn + scale. 1 thread.
__global__ void k_final(const Scal* __restrict__ s, float* __restrict__ out) {
    const double N = (double)IMG_B * (double)IMG_HW;
    const float gdenf = s->gmax - s->gmin + 1e-8f;
    const float ddenf = s->dmax - s->dmin + 1e-8f;
    const double a = 1.0 / (double)gdenf, bb = 1.0 / (double)ddenf;
    const double gmin = (double)s->gmin, dmin = (double)s->dmin;
    const double S_p = s->mom[0], S_pp = s->mom[1];
    const double S_g = s->mom[2], S_gg = s->mom[3], S_pg = s->mom[4];
    const double S_d = s->mom[5], S_dd = s->mom[6], S_pd = s->mom[7];
    const double S_t = s->mom[8];
    const double sum_g = S_pp - 2.0 * a * (S_pg - gmin * S_p)
                       + a * a * (S_gg - 2.0 * gmin * S_g + gmin * gmin * N);
    const double sum_d = S_pp - 2.0 * bb * (S_pd - dmin * S_p)
                       + bb * bb * (S_dd - 2.0 * dmin * S_d + dmin * dmin * N);
    const double sim = (sum_g + sum_d + S_t) / (3.0 * N);

    const double tp = (double)IMG_HW;
    const double tmin = 0.1 * tp, tmax = 0.3 * tp;
    double conn = 0.0, scale = 0.0;
    for (int b = 0; b < IMG_B; ++b) {
        const int total = s->fgcnt[b];
        if (total > 0) conn += 1.0 - (double)s->maxcnt[b] / (double)total;
        const double ar = s->area[b];
        scale += fmax(ar - tmax, 0.0) + fmax(tmin - ar, 0.0);
    }
    conn /= (double)IMG_B;
    scale = (scale / (double)IMG_B) / tp;
    const double total = sim + 0.1 * conn + 0.05 * scale;
    out[0] = (float)(0.1 * total);
}

extern "C" void kernel_launch(void* const* d_in, const int* in_sizes, int n_in,
                              void* d_out, int out_size, void* d_ws, size_t ws_size,
                              hipStream_t stream) {
    const float* pred = (const float*)d_in[0];  // [16,1,512,512]
    const float* dem  = (const float*)d_in[1];  // [16,1,512,512]
    float* out = (float*)d_out;

    char* ws = (char*)d_ws;
    Scal* s = (Scal*)ws;
    float4* pmm  = (float4*)(ws + OFF_PMM);
    double* pblk = (double*)(ws + OFF_MOM);
    int*    pfg  = (int*)(ws + OFF_FG);
    int* scratch = (int*)(ws + OFF_SCR);
    const size_t avail_ints = (ws_size > OFF_SCR) ? (ws_size - OFF_SCR) / 4 : 0;
    const size_t per_img = 2ull * NODES_PER_IMG + TILES + PAIRS;

    long long chunk = (long long)(avail_ints / per_img);
    if (chunk < 1) chunk = 1;
    if (chunk > IMG_B) chunk = IMG_B;

    for (int b0 = 0; b0 < IMG_B; b0 += (int)chunk) {
        const int n = (int)((b0 + chunk <= IMG_B) ? chunk : (IMG_B - b0));
        int* Lp      = scratch;
        int* Cp      = scratch + (size_t)chunk * NODES_PER_IMG;
        int* nslotp  = scratch + 2ull * chunk * NODES_PER_IMG;
        int* pairmax = nslotp + (size_t)chunk * TILES;
        const int featOn = (b0 == 0) ? 1 : 0;
        const int gx = featOn ? 320 : 64;
        const int gy = featOn ? IMG_B : n;
        hipLaunchKernelGGL(k_main, dim3(gx, gy), dim3(128), 0, stream,
                           dem, pred, pmm, pblk, pfg, Lp, Cp, nslotp, pairmax,
                           b0, n, featOn);
        hipLaunchKernelGGL(k_mid, dim3(featOn ? 86 : 60, n), dim3(256), 0, stream,
                           Lp, pmm, pblk, pfg, s);
        hipLaunchKernelGGL(k_tail, dim3(65, n), dim3(256), 0, stream,
                           Lp, Cp, nslotp, pairmax, s, b0);
    }

    hipLaunchKernelGGL(k_final, dim3(1), dim3(1), 0, stream, s, out);
}